// Round 1
// baseline (2015.716 us; speedup 1.0000x reference)
//
#include <hip/hip_runtime.h>
#include <math.h>
#include <stdint.h>

static constexpr int NN = 50000;      // graph nodes
static constexpr int EE = 800000;     // edges (no self loops)
static constexpr int ET = EE + NN;    // edges + self loops
static constexpr int BB = 8;
static constexpr int SS = 512;
static constexpr int HH = 768;
static constexpr int NC = 111;
static constexpr int NL = 50;

#define DINL __device__ __forceinline__

DINL float wsum(float v){
  #pragma unroll
  for (int m=1;m<64;m<<=1) v += __shfl_xor(v, m);
  return v;
}
DINL float wmax(float v){
  #pragma unroll
  for (int m=1;m<64;m<<=1) v = fmaxf(v, __shfl_xor(v, m));
  return v;
}
DINL float4 wsum4(float4 v){
  #pragma unroll
  for (int m=1;m<64;m<<=1){
    v.x += __shfl_xor(v.x,m); v.y += __shfl_xor(v.y,m);
    v.z += __shfl_xor(v.z,m); v.w += __shfl_xor(v.w,m);
  }
  return v;
}
DINL float4 wmax4(float4 v){
  #pragma unroll
  for (int m=1;m<64;m<<=1){
    v.x=fmaxf(v.x,__shfl_xor(v.x,m)); v.y=fmaxf(v.y,__shfl_xor(v.y,m));
    v.z=fmaxf(v.z,__shfl_xor(v.z,m)); v.w=fmaxf(v.w,__shfl_xor(v.w,m));
  }
  return v;
}

// ---------------- CSR build ----------------
__global__ void count_deg_k(const int* __restrict__ eidx, int* __restrict__ deg){
  int i = blockIdx.x*256 + threadIdx.x;
  if (i>=ET) return;
  int d = (i<EE)? eidx[EE + i] : (i - EE);
  atomicAdd(&deg[d], 1);
}

__global__ __launch_bounds__(1024) void scan_k(const int* __restrict__ deg, int* __restrict__ rowstart){
  __shared__ int sh[1024];
  __shared__ int carry_sh;
  int tid = threadIdx.x;
  if (tid==0) carry_sh = 0;
  __syncthreads();
  for (int base=0; base<NN; base+=1024){
    int i = base + tid;
    int v = (i<NN)? deg[i] : 0;
    sh[tid] = v;
    __syncthreads();
    for (int off=1; off<1024; off<<=1){
      int t = (tid>=off)? sh[tid-off] : 0;
      __syncthreads();
      sh[tid] += t;
      __syncthreads();
    }
    int carry = carry_sh;
    if (i<NN) rowstart[i] = carry + sh[tid] - v;
    __syncthreads();
    if (tid==1023) carry_sh = carry + sh[1023];
    __syncthreads();
  }
  if (tid==0) rowstart[NN] = carry_sh;
}

__global__ void fill_csr_k(const int* __restrict__ eidx, const int* __restrict__ rowstart,
                           int* __restrict__ cursor, int* __restrict__ csr_src, int* __restrict__ csr_dst){
  int i = blockIdx.x*256 + threadIdx.x;
  if (i>=ET) return;
  int s, d;
  if (i<EE){ s = eidx[i]; d = eidx[EE+i]; } else { s = i-EE; d = i-EE; }
  int pos = rowstart[d] + atomicAdd(&cursor[d], 1);
  csr_src[pos] = s; csr_dst[pos] = d;
}

// ---------------- generic f32 GEMM ----------------
// C[m,n] = act(alpha * sum_k A[m,k]*B'[k,n] + bias[n]); B' = B (KxN) or B^T (B is NxK) if TB
template<bool TB>
__global__ __launch_bounds__(256) void gemm_f32(
    const float* __restrict__ A, const float* __restrict__ Bm,
    const float* __restrict__ bias, float* __restrict__ C,
    int M, int N, int K, int lda, int ldb, int ldc,
    int nb2,
    int64_t sA1, int64_t sA2, int64_t sB1, int64_t sB2, int64_t sC1, int64_t sC2,
    float alpha, int act)
{
  int z = blockIdx.z;
  int z1 = z / nb2, z2 = z - z1*nb2;
  A  += z1*sA1 + z2*sA2;
  Bm += z1*sB1 + z2*sB2;
  C  += z1*sC1 + z2*sC2;
  __shared__ float sA[16][68];
  __shared__ float sB[16][68];
  const int tid = threadIdx.x;
  const int m0 = blockIdx.y*64, n0 = blockIdx.x*64;
  const int tx = tid & 15, ty = tid >> 4;
  float acc[4][4] = {};
  for (int k0=0; k0<K; k0+=16){
    {
      int kk = tid & 15, mm = tid >> 4;
      #pragma unroll
      for (int r=0;r<4;r++){
        int m = m0 + mm + r*16, k = k0 + kk;
        float v = 0.f;
        if (m<M && k<K) v = A[(int64_t)m*lda + k];
        sA[kk][mm + r*16] = v;
      }
    }
    if (!TB){
      int nn = tid & 63, kb = tid >> 6;
      #pragma unroll
      for (int r=0;r<4;r++){
        int k = k0 + kb + r*4, n = n0 + nn;
        float v=0.f;
        if (k<K && n<N) v = Bm[(int64_t)k*ldb + n];
        sB[kb + r*4][nn] = v;
      }
    } else {
      int kk = tid & 15, nn = tid >> 4;
      #pragma unroll
      for (int r=0;r<4;r++){
        int n = n0 + nn + r*16, k = k0 + kk;
        float v=0.f;
        if (n<N && k<K) v = Bm[(int64_t)n*ldb + k];
        sB[kk][nn + r*16] = v;
      }
    }
    __syncthreads();
    #pragma unroll
    for (int k=0;k<16;k++){
      float a0=sA[k][ty*4+0],a1=sA[k][ty*4+1],a2=sA[k][ty*4+2],a3=sA[k][ty*4+3];
      float b0=sB[k][tx*4+0],b1=sB[k][tx*4+1],b2=sB[k][tx*4+2],b3=sB[k][tx*4+3];
      acc[0][0]+=a0*b0; acc[0][1]+=a0*b1; acc[0][2]+=a0*b2; acc[0][3]+=a0*b3;
      acc[1][0]+=a1*b0; acc[1][1]+=a1*b1; acc[1][2]+=a1*b2; acc[1][3]+=a1*b3;
      acc[2][0]+=a2*b0; acc[2][1]+=a2*b1; acc[2][2]+=a2*b2; acc[2][3]+=a2*b3;
      acc[3][0]+=a3*b0; acc[3][1]+=a3*b1; acc[3][2]+=a3*b2; acc[3][3]+=a3*b3;
    }
    __syncthreads();
  }
  #pragma unroll
  for (int i=0;i<4;i++){
    int m = m0 + ty*4 + i;
    if (m>=M) continue;
    #pragma unroll
    for (int j=0;j<4;j++){
      int n = n0 + tx*4 + j;
      if (n>=N) continue;
      float v = acc[i][j]*alpha;
      if (bias) v += bias[n];
      if (act==1) v = tanhf(v);
      C[(int64_t)m*ldc + n] = v;
    }
  }
}

// ---------------- GAT helpers ----------------
__global__ __launch_bounds__(256) void attcoef1_k(const float* __restrict__ h,
    const float* __restrict__ a_src, const float* __restrict__ a_dst,
    float* __restrict__ asrc, float* __restrict__ adst){
  int node = blockIdx.x*4 + (threadIdx.x>>6);
  if (node>=NN) return;
  int lane = threadIdx.x & 63;
  float4 hv = ((const float4*)h)[(int64_t)node*64 + lane];
  int head = lane >> 4;
  float4 as = ((const float4*)a_src)[head*16 + (lane&15)];
  float4 ad = ((const float4*)a_dst)[head*16 + (lane&15)];
  float ps = hv.x*as.x + hv.y*as.y + hv.z*as.z + hv.w*as.w;
  float pd = hv.x*ad.x + hv.y*ad.y + hv.z*ad.z + hv.w*ad.w;
  #pragma unroll
  for (int m=1;m<16;m<<=1){ ps += __shfl_xor(ps,m); pd += __shfl_xor(pd,m); }
  if ((lane&15)==0){ asrc[node*4+head]=ps; adst[node*4+head]=pd; }
}

__global__ __launch_bounds__(256) void attcoef2_k(const float* __restrict__ h,
    const float* __restrict__ a_src, const float* __restrict__ a_dst,
    float* __restrict__ asrc, float* __restrict__ adst){
  int node = blockIdx.x*4 + (threadIdx.x>>6);
  if (node>=NN) return;
  int lane = threadIdx.x & 63;
  float4 hv = ((const float4*)h)[(int64_t)node*64 + lane];
  float4 as = ((const float4*)a_src)[lane];
  float4 ad = ((const float4*)a_dst)[lane];
  float ps = hv.x*as.x + hv.y*as.y + hv.z*as.z + hv.w*as.w;
  float pd = hv.x*ad.x + hv.y*ad.y + hv.z*ad.z + hv.w*ad.w;
  ps = wsum(ps); pd = wsum(pd);
  if (lane==0){ asrc[node]=ps; adst[node]=pd; }
}

__global__ void edge_e1_k(const int* __restrict__ csr_src, const int* __restrict__ csr_dst,
                          const float* __restrict__ asrc, const float* __restrict__ adst,
                          float* __restrict__ ebuf){
  int p = blockIdx.x*256 + threadIdx.x;
  if (p>=ET) return;
  int s = csr_src[p], d = csr_dst[p];
  float4 a = ((const float4*)asrc)[s];
  float4 b = ((const float4*)adst)[d];
  float4 e;
  e.x = a.x+b.x; e.x = (e.x>=0.f)? e.x : 0.2f*e.x;
  e.y = a.y+b.y; e.y = (e.y>=0.f)? e.y : 0.2f*e.y;
  e.z = a.z+b.z; e.z = (e.z>=0.f)? e.z : 0.2f*e.z;
  e.w = a.w+b.w; e.w = (e.w>=0.f)? e.w : 0.2f*e.w;
  ((float4*)ebuf)[p] = e;
}

__global__ void edge_e2_k(const int* __restrict__ csr_src, const int* __restrict__ csr_dst,
                          const float* __restrict__ asrc, const float* __restrict__ adst,
                          float* __restrict__ ebuf){
  int p = blockIdx.x*256 + threadIdx.x;
  if (p>=ET) return;
  int s = csr_src[p], d = csr_dst[p];
  float e = asrc[s] + adst[d];
  e = (e>=0.f)? e : 0.2f*e;
  ebuf[p] = e;
}

// layer1: 4 heads of 64ch; lane covers channels 4*lane..4*lane+3 (head = lane>>4). +bias, elu.
__global__ __launch_bounds__(256) void agg1_k(const float* __restrict__ h, const float* __restrict__ ebuf,
    const int* __restrict__ rowstart, const int* __restrict__ csr_src,
    const float* __restrict__ bias, float* __restrict__ outp){
  int node = blockIdx.x*4 + (threadIdx.x>>6);
  if (node>=NN) return;
  int lane = threadIdx.x & 63;
  int rs = rowstart[node], re = rowstart[node+1];
  const float4* e4 = (const float4*)ebuf;
  float4 mx = make_float4(-INFINITY,-INFINITY,-INFINITY,-INFINITY);
  for (int p=rs+lane; p<re; p+=64){
    float4 e = e4[p];
    mx.x=fmaxf(mx.x,e.x); mx.y=fmaxf(mx.y,e.y); mx.z=fmaxf(mx.z,e.z); mx.w=fmaxf(mx.w,e.w);
  }
  mx = wmax4(mx);
  float4 sm = make_float4(0.f,0.f,0.f,0.f);
  for (int p=rs+lane; p<re; p+=64){
    float4 e = e4[p];
    sm.x += expf(e.x-mx.x); sm.y += expf(e.y-mx.y);
    sm.z += expf(e.z-mx.z); sm.w += expf(e.w-mx.w);
  }
  sm = wsum4(sm);
  int head = lane>>4;
  float m_h = head==0?mx.x:head==1?mx.y:head==2?mx.z:mx.w;
  float s_h = head==0?sm.x:head==1?sm.y:head==2?sm.z:sm.w;
  float dinv = 1.f/(s_h+1e-16f);
  const float4* h4 = (const float4*)h;
  float4 acc = make_float4(0.f,0.f,0.f,0.f);
  for (int p=rs; p<re; ++p){
    int s = csr_src[p];
    float w = expf(ebuf[p*4+head]-m_h)*dinv;
    float4 hv = h4[(int64_t)s*64 + lane];
    acc.x += w*hv.x; acc.y += w*hv.y; acc.z += w*hv.z; acc.w += w*hv.w;
  }
  float4 bb = ((const float4*)bias)[lane];
  float4 o;
  o.x = acc.x+bb.x; o.x = (o.x>0.f)? o.x : expm1f(o.x);
  o.y = acc.y+bb.y; o.y = (o.y>0.f)? o.y : expm1f(o.y);
  o.z = acc.z+bb.z; o.z = (o.z>0.f)? o.z : expm1f(o.z);
  o.w = acc.w+bb.w; o.w = (o.w>0.f)? o.w : expm1f(o.w);
  ((float4*)outp)[(int64_t)node*64 + lane] = o;
}

// layer2: single head over 256 ch. +bias, no act.
__global__ __launch_bounds__(256) void agg2_k(const float* __restrict__ h, const float* __restrict__ ebuf,
    const int* __restrict__ rowstart, const int* __restrict__ csr_src,
    const float* __restrict__ bias, float* __restrict__ outp){
  int node = blockIdx.x*4 + (threadIdx.x>>6);
  if (node>=NN) return;
  int lane = threadIdx.x & 63;
  int rs = rowstart[node], re = rowstart[node+1];
  float mx = -INFINITY;
  for (int p=rs+lane; p<re; p+=64) mx = fmaxf(mx, ebuf[p]);
  mx = wmax(mx);
  float sm = 0.f;
  for (int p=rs+lane; p<re; p+=64) sm += expf(ebuf[p]-mx);
  sm = wsum(sm);
  float dinv = 1.f/(sm+1e-16f);
  const float4* h4 = (const float4*)h;
  float4 acc = make_float4(0.f,0.f,0.f,0.f);
  for (int p=rs; p<re; ++p){
    int s = csr_src[p];
    float w = expf(ebuf[p]-mx)*dinv;
    float4 hv = h4[(int64_t)s*64 + lane];
    acc.x += w*hv.x; acc.y += w*hv.y; acc.z += w*hv.z; acc.w += w*hv.w;
  }
  float4 bb = ((const float4*)bias)[lane];
  float4 o = make_float4(acc.x+bb.x, acc.y+bb.y, acc.z+bb.z, acc.w+bb.w);
  ((float4*)outp)[(int64_t)node*64 + lane] = o;
}

// ---------------- small glue kernels ----------------
__global__ void gather_gsel_k(const float* __restrict__ out2, const int* __restrict__ cidx,
                              float* __restrict__ gsel){
  int idx = blockIdx.x*256 + threadIdx.x;
  if (idx >= NC*256) return;
  int i = idx >> 8, c = idx & 255;
  gsel[idx] = out2[(int64_t)cidx[i]*256 + c];
}

__global__ void build_fused_k(const float* __restrict__ bert, const float* __restrict__ gatc,
                              float* __restrict__ fused){
  int idx = blockIdx.x*256 + threadIdx.x;
  if (idx >= NC*1536) return;
  int i = idx / 1536, c = idx - i*1536;
  fused[idx] = (c<768)? bert[(int64_t)i*768 + c] : gatc[(int64_t)i*768 + (c-768)];
}

// LN over last dim 768 (optionally x = x1 + sigmoid(*gs)*x2), optional relu
__global__ __launch_bounds__(256) void ln_k(const float* __restrict__ x1, const float* __restrict__ x2,
    const float* __restrict__ gsptr, const float* __restrict__ g, const float* __restrict__ bb,
    float* __restrict__ outp, int relu){
  __shared__ float red[4];
  int row = blockIdx.x;
  int t = threadIdx.x;
  float gs = 0.f;
  if (x2) gs = 1.f/(1.f+expf(-gsptr[0]));
  const float* xr = x1 + (int64_t)row*768;
  float v0 = xr[t], v1 = xr[t+256], v2 = xr[t+512];
  if (x2){
    const float* x2r = x2 + (int64_t)row*768;
    v0 += gs*x2r[t]; v1 += gs*x2r[t+256]; v2 += gs*x2r[t+512];
  }
  int lane = t&63, wid = t>>6;
  float s = wsum(v0+v1+v2);
  if (lane==0) red[wid]=s;
  __syncthreads();
  float mean = (red[0]+red[1]+red[2]+red[3]) * (1.f/768.f);
  __syncthreads();
  float d0=v0-mean, d1=v1-mean, d2=v2-mean;
  float ss = wsum(d0*d0+d1*d1+d2*d2);
  if (lane==0) red[wid]=ss;
  __syncthreads();
  float var = (red[0]+red[1]+red[2]+red[3]) * (1.f/768.f);
  float rstd = rsqrtf(var + 1e-5f);
  float o0 = d0*rstd*g[t]+bb[t];
  float o1 = d1*rstd*g[t+256]+bb[t+256];
  float o2 = d2*rstd*g[t+512]+bb[t+512];
  if (relu){ o0=fmaxf(o0,0.f); o1=fmaxf(o1,0.f); o2=fmaxf(o2,0.f); }
  float* orow = outp + (int64_t)row*768;
  orow[t]=o0; orow[t+256]=o1; orow[t+512]=o2;
}

// softmax over last dim (NC=111) for rows of scores, in place
__global__ __launch_bounds__(256) void softmax_nc_k(float* __restrict__ sc, int rows){
  int row = blockIdx.x*4 + (threadIdx.x>>6);
  if (row>=rows) return;
  int lane = threadIdx.x & 63;
  float* r = sc + (int64_t)row*NC;
  float x0 = r[lane];
  float x1 = (lane+64<NC)? r[lane+64] : -INFINITY;
  float m = wmax(fmaxf(x0,x1));
  float p0 = expf(x0-m);
  float p1 = (lane+64<NC)? expf(x1-m) : 0.f;
  float s = wsum(p0+p1);
  float dinv = 1.f/s;
  r[lane] = p0*dinv;
  if (lane+64<NC) r[lane+64] = p1*dinv;
}

__global__ void mean_heads_k(const float* __restrict__ attn, float* __restrict__ outp){
  int64_t idx = (int64_t)blockIdx.x*256 + threadIdx.x;
  if (idx >= (int64_t)BB*SS*NC) return;
  int c = idx % NC;
  int64_t r = idx / NC;
  int s = r % SS;
  int b = r / SS;
  float acc = 0.f;
  #pragma unroll
  for (int h=0;h<8;h++)
    acc += attn[(((int64_t)(b*8+h)*SS)+s)*NC + c];
  outp[idx] = acc * 0.125f;
}

__global__ void sigmoid_k(const float* __restrict__ in, float* __restrict__ outp, int n,
                          const float* __restrict__ gsptr, float* __restrict__ gsout){
  int idx = blockIdx.x*256 + threadIdx.x;
  if (idx < n) outp[idx] = 1.f/(1.f+expf(-in[idx]));
  if (idx == 0) gsout[0] = 1.f/(1.f+expf(-gsptr[0]));
}

// softmax over S (axis=1) per (b,l), in place, with mask
__global__ __launch_bounds__(256) void laat_softmax_k(float* __restrict__ att, const int* __restrict__ mask){
  int idx = blockIdx.x*4 + (threadIdx.x>>6);
  if (idx >= BB*NL) return;
  int lane = threadIdx.x & 63;
  int b = idx / NL, l = idx - b*NL;
  float x[8];
  #pragma unroll
  for (int i=0;i<8;i++){
    int s = lane + i*64;
    int mk = mask[b*SS + s];
    x[i] = mk ? att[((int64_t)(b*SS+s))*NL + l] : -INFINITY;
  }
  float m = -INFINITY;
  #pragma unroll
  for (int i=0;i<8;i++) m = fmaxf(m, x[i]);
  m = wmax(m);
  float p[8]; float sm = 0.f;
  #pragma unroll
  for (int i=0;i<8;i++){ p[i] = expf(x[i]-m); sm += p[i]; }
  sm = wsum(sm);
  float dinv = 1.f/sm;
  #pragma unroll
  for (int i=0;i<8;i++){
    int s = lane + i*64;
    att[((int64_t)(b*SS+s))*NL + l] = p[i]*dinv;
  }
}

// label_reps[b,l,:] = sum_s w[b,s,l] * enr[b,s,:]
__global__ __launch_bounds__(256) void label_reps_k(const float* __restrict__ w,
    const float* __restrict__ enr, float* __restrict__ outp){
  int bl = blockIdx.x;
  int b = bl / NL, l = bl - b*NL;
  int t = threadIdx.x;
  const float* wb = w + (int64_t)b*SS*NL + l;
  const float* eb = enr + (int64_t)b*SS*768;
  float a0=0.f, a1=0.f, a2=0.f;
  for (int s=0;s<SS;s++){
    float wv = wb[(int64_t)s*NL];
    const float* row = eb + (int64_t)s*768;
    a0 += wv*row[t]; a1 += wv*row[t+256]; a2 += wv*row[t+512];
  }
  float* o = outp + (int64_t)bl*768;
  o[t]=a0; o[t+256]=a1; o[t+512]=a2;
}

__global__ __launch_bounds__(256) void logits_k(const float* __restrict__ lr,
    const float* __restrict__ low, const float* __restrict__ lob,
    const float* __restrict__ cs, const float* __restrict__ c2l,
    float* __restrict__ logits){
  int idx = blockIdx.x*4 + (threadIdx.x>>6);
  if (idx >= BB*NL) return;
  int lane = threadIdx.x & 63;
  int b = idx / NL, l = idx - b*NL;
  const float* r = lr + (int64_t)idx*768;
  float acc = 0.f;
  for (int c=lane;c<768;c+=64) acc += r[c]*low[c];
  for (int c=lane;c<NC;c+=64)  acc += cs[b*NC+c]*c2l[l*NC+c];
  acc = wsum(acc);
  if (lane==0) logits[idx] = acc + lob[0];
}

// ---------------- host ----------------
extern "C" void kernel_launch(void* const* d_in, const int* in_sizes, int n_in,
                              void* d_out, int out_size, void* d_ws, size_t ws_size,
                              hipStream_t stream)
{
  const float* hs    = (const float*)d_in[0];
  const int*   amask = (const int*)d_in[1];
  const float* bert  = (const float*)d_in[2];
  const float* gx    = (const float*)d_in[3];
  const int*   eidx  = (const int*)d_in[4];
  const int*   cidx  = (const int*)d_in[5];
  const float* w1    = (const float*)d_in[6];
  const float* as1   = (const float*)d_in[7];
  const float* ad1   = (const float*)d_in[8];
  const float* b1    = (const float*)d_in[9];
  const float* w2    = (const float*)d_in[10];
  const float* as2   = (const float*)d_in[11];
  const float* ad2   = (const float*)d_in[12];
  const float* b2    = (const float*)d_in[13];
  const float* gpw   = (const float*)d_in[14];
  const float* gpb   = (const float*)d_in[15];
  const float* fw    = (const float*)d_in[16];
  const float* fb    = (const float*)d_in[17];
  const float* flng  = (const float*)d_in[18];
  const float* flnb  = (const float*)d_in[19];
  const float* ipw   = (const float*)d_in[20];
  const float* ipb   = (const float*)d_in[21];
  const float* opw   = (const float*)d_in[22];
  const float* opb   = (const float*)d_in[23];
  const float* lng   = (const float*)d_in[24];
  const float* lnb   = (const float*)d_in[25];
  const float* chw   = (const float*)d_in[26];
  const float* chb   = (const float*)d_in[27];
  const float* lfw   = (const float*)d_in[28];
  const float* lsw   = (const float*)d_in[29];
  const float* low   = (const float*)d_in[30];
  const float* lob   = (const float*)d_in[31];
  const float* c2l   = (const float*)d_in[32];
  const float* gsc   = (const float*)d_in[33];
  float* out = (float*)d_out;

  // workspace layout
  int* deg      = (int*)d_ws;
  int* cursor   = deg + NN;
  int* rowstart = cursor + NN;
  int* csr_src  = rowstart + (NN+1);
  int* csr_dst  = csr_src + ET;
  size_t iw = (size_t)NN*2 + (size_t)(NN+1) + (size_t)ET*2;
  float* fbase = (float*)d_ws + ((iw+3) & ~(size_t)3);
  float* ebuf  = fbase;                        // ET*4
  float* asrcb = ebuf  + (size_t)ET*4;         // NN*4
  float* adstb = asrcb + (size_t)NN*4;         // NN*4
  float* bufA  = adstb + (size_t)NN*4;         // NN*256
  float* bufB  = bufA  + (size_t)NN*256;       // NN*256
  float* gselb = bufB  + (size_t)NN*256;       // NC*256
  float* gatc  = gselb + (size_t)NC*256;       // NC*768
  float* fusedb= gatc  + (size_t)NC*HH;        // NC*1536
  float* kvb   = fusedb+ (size_t)NC*1536;      // NC*1536
  float* enhb  = kvb   + (size_t)NC*1536;      // NC*768
  // overlays (lifetimes disjoint with bufA/bufB graph contents)
  float* qb    = bufA;                                  // B*S*H
  float* scb   = bufA + (size_t)BB*SS*HH;               // B*8*S*NC
  float* ctxb  = scb  + (size_t)BB*8*SS*NC;             // B*S*H
  float* ctxt  = bufB;                                  // B*S*H
  float* enrb  = bufB + (size_t)BB*SS*HH;               // B*S*H
  float* Ub    = enrb + (size_t)BB*SS*HH;               // B*S*H
  float* attb  = Ub   + (size_t)BB*SS*HH;               // B*S*NL

  float* out_logits = out;
  float* out_cl = out + 400;
  float* out_cs = out + 1288;
  float* out_lr = out + 2176;
  float* out_aw = out + 309376;
  float* out_gs = out + 764032;

  hipMemsetAsync(deg,    0, sizeof(int)*NN, stream);
  hipMemsetAsync(cursor, 0, sizeof(int)*NN, stream);

  count_deg_k<<<(ET+255)/256,256,0,stream>>>(eidx, deg);
  scan_k<<<1,1024,0,stream>>>(deg, rowstart);
  fill_csr_k<<<(ET+255)/256,256,0,stream>>>(eidx, rowstart, cursor, csr_src, csr_dst);

  auto gemm = [&](bool tb, const float* A, const float* Bm, const float* bias, float* C,
                  int M, int Nn, int K, int lda, int ldb, int ldc,
                  int nb, int nb2,
                  int64_t sA1,int64_t sA2,int64_t sB1,int64_t sB2,int64_t sC1,int64_t sC2,
                  float alpha, int act){
    dim3 g((Nn+63)/64, (M+63)/64, nb);
    if (tb) gemm_f32<true ><<<g,256,0,stream>>>(A,Bm,bias,C,M,Nn,K,lda,ldb,ldc,nb2,sA1,sA2,sB1,sB2,sC1,sC2,alpha,act);
    else    gemm_f32<false><<<g,256,0,stream>>>(A,Bm,bias,C,M,Nn,K,lda,ldb,ldc,nb2,sA1,sA2,sB1,sB2,sC1,sC2,alpha,act);
  };

  // ---- GAT layer 1 ----
  gemm(false, gx, w1, nullptr, bufA, NN, 256, 256, 256,256,256, 1,1, 0,0,0,0,0,0, 1.f, 0);
  attcoef1_k<<<(NN+3)/4,256,0,stream>>>(bufA, as1, ad1, asrcb, adstb);
  edge_e1_k<<<(ET+255)/256,256,0,stream>>>(csr_src, csr_dst, asrcb, adstb, ebuf);
  agg1_k<<<(NN+3)/4,256,0,stream>>>(bufA, ebuf, rowstart, csr_src, b1, bufB);
  // ---- GAT layer 2 ----
  gemm(false, bufB, w2, nullptr, bufA, NN, 256, 256, 256,256,256, 1,1, 0,0,0,0,0,0, 1.f, 0);
  attcoef2_k<<<(NN+3)/4,256,0,stream>>>(bufA, as2, ad2, asrcb, adstb);
  edge_e2_k<<<(ET+255)/256,256,0,stream>>>(csr_src, csr_dst, asrcb, adstb, ebuf);
  agg2_k<<<(NN+3)/4,256,0,stream>>>(bufA, ebuf, rowstart, csr_src, b2, bufB);
  // ---- concept path ----
  gather_gsel_k<<<(NC*256+255)/256,256,0,stream>>>(bufB, cidx, gselb);
  gemm(true, gselb, gpw, gpb, gatc, NC, HH, 256, 256,256,HH, 1,1, 0,0,0,0,0,0, 1.f, 0);
  build_fused_k<<<(NC*1536+255)/256,256,0,stream>>>(bert, gatc, fusedb);
  gemm(true, fusedb, fw, fb, enhb, NC, HH, 1536, 1536,1536,HH, 1,1, 0,0,0,0,0,0, 1.f, 0);
  ln_k<<<NC,256,0,stream>>>(enhb, nullptr, nullptr, flng, flnb, enhb, 1);
  // K,V for enhanced rows (same for all batches)
  gemm(true, enhb, ipw + (size_t)768*768, ipb+768, kvb, NC, 1536, 768, 768,768,1536, 1,1, 0,0,0,0,0,0, 1.f, 0);
  // Q
  gemm(true, hs, ipw, ipb, qb, BB*SS, HH, HH, 768,768,768, 1,1, 0,0,0,0,0,0, 1.f, 0);
  // scores[b,h]: (512x96)@(111x96)^T / sqrt(96)
  gemm(true, qb, kvb, nullptr, scb, SS, NC, 96, 768, 1536, NC, BB*8, 8,
       (int64_t)SS*HH, 96, 0, 96, (int64_t)8*SS*NC, (int64_t)SS*NC, 0.10206207261596577f, 0);
  softmax_nc_k<<<(BB*8*SS)/4,256,0,stream>>>(scb, BB*8*SS);
  mean_heads_k<<<(int)(((int64_t)BB*SS*NC+255)/256),256,0,stream>>>(scb, out_aw);
  // ctx[b,h]: (512x111)@(111x96)
  gemm(false, scb, kvb+768, nullptr, ctxb, SS, 96, NC, NC, 1536, HH, BB*8, 8,
       (int64_t)8*SS*NC, (int64_t)SS*NC, 0, 96, (int64_t)SS*HH, 96, 1.f, 0);
  gemm(true, ctxb, opw, opb, ctxt, BB*SS, HH, HH, 768,768,768, 1,1, 0,0,0,0,0,0, 1.f, 0);
  // concept logits / scores
  gemm(true, hs, chw, chb, out_cl, BB, NC, HH, SS*HH, 768, NC, 1,1, 0,0,0,0,0,0, 1.f, 0);
  sigmoid_k<<<4,256,0,stream>>>(out_cl, out_cs, BB*NC, gsc, out_gs);
  // enriched = LN(hs + sigmoid(gs)*context)
  ln_k<<<BB*SS,256,0,stream>>>(hs, ctxt, gsc, lng, lnb, enrb, 0);
  // LAAT
  gemm(true, enrb, lfw, nullptr, Ub, BB*SS, HH, HH, 768,768,768, 1,1, 0,0,0,0,0,0, 1.f, 1);
  gemm(true, Ub, lsw, nullptr, attb, BB*SS, NL, HH, 768,768,NL, 1,1, 0,0,0,0,0,0, 1.f, 0);
  laat_softmax_k<<<(BB*NL+3)/4,256,0,stream>>>(attb, amask);
  label_reps_k<<<BB*NL,256,0,stream>>>(attb, enrb, out_lr);
  logits_k<<<(BB*NL+3)/4,256,0,stream>>>(out_lr, low, lob, out_cs, c2l, out_logits);
}

// Round 4
// 1813.447 us; speedup vs baseline: 1.1115x; 1.1115x over previous
//
#include <hip/hip_runtime.h>
#include <math.h>
#include <stdint.h>

static constexpr int NN = 50000;      // graph nodes
static constexpr int EE = 800000;     // edges (no self loops)
static constexpr int ET = EE + NN;    // edges + self loops
static constexpr int BB = 8;
static constexpr int SS = 512;
static constexpr int HH = 768;
static constexpr int NC = 111;
static constexpr int NL = 50;

#define DINL __device__ __forceinline__

DINL float wsum(float v){
  #pragma unroll
  for (int m=1;m<64;m<<=1) v += __shfl_xor(v, m);
  return v;
}
DINL float wmax(float v){
  #pragma unroll
  for (int m=1;m<64;m<<=1) v = fmaxf(v, __shfl_xor(v, m));
  return v;
}
DINL float4 wsum4(float4 v){
  #pragma unroll
  for (int m=1;m<64;m<<=1){
    v.x += __shfl_xor(v.x,m); v.y += __shfl_xor(v.y,m);
    v.z += __shfl_xor(v.z,m); v.w += __shfl_xor(v.w,m);
  }
  return v;
}
DINL float4 wmax4(float4 v){
  #pragma unroll
  for (int m=1;m<64;m<<=1){
    v.x=fmaxf(v.x,__shfl_xor(v.x,m)); v.y=fmaxf(v.y,__shfl_xor(v.y,m));
    v.z=fmaxf(v.z,__shfl_xor(v.z,m)); v.w=fmaxf(v.w,__shfl_xor(v.w,m));
  }
  return v;
}

// ---------------- CSR build ----------------
__global__ void count_deg_k(const int* __restrict__ eidx, int* __restrict__ deg){
  int i = blockIdx.x*256 + threadIdx.x;
  if (i>=ET) return;
  int d = (i<EE)? eidx[EE + i] : (i - EE);
  atomicAdd(&deg[d], 1);
}

// hierarchical scan: 1024-chunk inclusive scans + chunk sums
__global__ __launch_bounds__(1024) void scan1_k(const int* __restrict__ deg,
                                                int* __restrict__ incl, int* __restrict__ csum){
  __shared__ int sh[1024];
  int tid = threadIdx.x;
  int i = blockIdx.x*1024 + tid;
  int v = (i<NN)? deg[i] : 0;
  sh[tid] = v;
  __syncthreads();
  for (int off=1; off<1024; off<<=1){
    int t = (tid>=off)? sh[tid-off] : 0;
    __syncthreads();
    sh[tid] += t;
    __syncthreads();
  }
  if (i<NN) incl[i] = sh[tid];
  if (tid==1023) csum[blockIdx.x] = sh[1023];
}

__global__ void scan2_k(int* __restrict__ csum, int nch){
  if (threadIdx.x==0 && blockIdx.x==0){
    int run = 0;
    for (int i=0;i<nch;i++){ int v = csum[i]; csum[i] = run; run += v; }
  }
}

__global__ void scan3_k(const int* __restrict__ deg, const int* __restrict__ incl,
                        const int* __restrict__ csum, int* __restrict__ rowstart){
  int i = blockIdx.x*256 + threadIdx.x;
  if (i>=NN) return;
  int ex = csum[i>>10] + incl[i] - deg[i];
  rowstart[i] = ex;
  if (i==NN-1) rowstart[NN] = ex + deg[i];
}

__global__ void fill_csr_k(const int* __restrict__ eidx, const int* __restrict__ rowstart,
                           int* __restrict__ cursor, int* __restrict__ csr_src, int* __restrict__ csr_dst){
  int i = blockIdx.x*256 + threadIdx.x;
  if (i>=ET) return;
  int s, d;
  if (i<EE){ s = eidx[i]; d = eidx[EE+i]; } else { s = i-EE; d = i-EE; }
  int pos = rowstart[d] + atomicAdd(&cursor[d], 1);
  csr_src[pos] = s; csr_dst[pos] = d;
}

// ---------------- generic f32 GEMM (128x64 tile, 8x4 per-thread) ----------------
// C[m,n] = act(alpha * sum_k A[m,k]*B'[k,n] + bias[n]); B' = B (KxN) or B^T (B is NxK) if TB
template<bool TB>
__global__ __launch_bounds__(256) void gemm_f32(
    const float* __restrict__ A, const float* __restrict__ Bm,
    const float* __restrict__ bias, float* __restrict__ C,
    int M, int N, int K, int lda, int ldb, int ldc,
    int nb2,
    int64_t sA1, int64_t sA2, int64_t sB1, int64_t sB2, int64_t sC1, int64_t sC2,
    float alpha, int act)
{
  int z = blockIdx.z;
  int z1 = z / nb2, z2 = z - z1*nb2;
  A  += z1*sA1 + z2*sA2;
  Bm += z1*sB1 + z2*sB2;
  C  += z1*sC1 + z2*sC2;
  __shared__ __align__(16) float sA[16][132];
  __shared__ __align__(16) float sB[16][68];
  const int tid = threadIdx.x;
  const int m0 = blockIdx.y*128, n0 = blockIdx.x*64;
  const int tx = tid & 15, ty = tid >> 4;
  float acc[8][4] = {};
  for (int k0=0; k0<K; k0+=16){
    {
      int kk = tid & 15, mm = tid >> 4;
      #pragma unroll
      for (int r=0;r<8;r++){
        int m = m0 + mm + r*16, k = k0 + kk;
        float v = 0.f;
        if (m<M && k<K) v = A[(int64_t)m*lda + k];
        sA[kk][mm + r*16] = v;
      }
    }
    if (!TB){
      int nn = tid & 63, kb = tid >> 6;
      #pragma unroll
      for (int r=0;r<4;r++){
        int k = k0 + kb + r*4, n = n0 + nn;
        float v=0.f;
        if (k<K && n<N) v = Bm[(int64_t)k*ldb + n];
        sB[kb + r*4][nn] = v;
      }
    } else {
      int kk = tid & 15, nn = tid >> 4;
      #pragma unroll
      for (int r=0;r<4;r++){
        int n = n0 + nn + r*16, k = k0 + kk;
        float v=0.f;
        if (n<N && k<K) v = Bm[(int64_t)n*ldb + k];
        sB[kk][nn + r*16] = v;
      }
    }
    __syncthreads();
    #pragma unroll
    for (int k=0;k<16;k++){
      float4 a0 = *(const float4*)&sA[k][ty*8];
      float4 a1 = *(const float4*)&sA[k][ty*8+4];
      float4 b  = *(const float4*)&sB[k][tx*4];
      float av[8] = {a0.x,a0.y,a0.z,a0.w,a1.x,a1.y,a1.z,a1.w};
      float bv[4] = {b.x,b.y,b.z,b.w};
      #pragma unroll
      for (int i=0;i<8;i++)
        #pragma unroll
        for (int j=0;j<4;j++)
          acc[i][j] += av[i]*bv[j];
    }
    __syncthreads();
  }
  #pragma unroll
  for (int i=0;i<8;i++){
    int m = m0 + ty*8 + i;
    if (m>=M) continue;
    #pragma unroll
    for (int j=0;j<4;j++){
      int n = n0 + tx*4 + j;
      if (n>=N) continue;
      float v = acc[i][j]*alpha;
      if (bias) v += bias[n];
      if (act==1) v = tanhf(v);
      C[(int64_t)m*ldc + n] = v;
    }
  }
}

// ---------------- skinny GEMM: C[M,N] = A[M,K] @ B[N,K]^T + bias ----------------
// one wave per (row m, 4 columns). K must be a multiple of 4.
__global__ __launch_bounds__(256) void skinny_tb_k(
    const float* __restrict__ A, const float* __restrict__ B,
    const float* __restrict__ bias, float* __restrict__ C,
    int M, int N, int K, int lda, int ldb, int ldc)
{
  int ngroups = (N+3)>>2;
  int w = blockIdx.x*4 + (threadIdx.x>>6);
  if (w >= M*ngroups) return;
  int lane = threadIdx.x & 63;
  int m = w / ngroups, ng = w - m*ngroups;
  int n0 = ng*4;
  const float4* a4 = (const float4*)(A + (int64_t)m*lda);
  int r0 = n0, r1 = (n0+1<N)? n0+1 : N-1, r2 = (n0+2<N)? n0+2 : N-1, r3 = (n0+3<N)? n0+3 : N-1;
  const float4* b0 = (const float4*)(B + (int64_t)r0*ldb);
  const float4* b1 = (const float4*)(B + (int64_t)r1*ldb);
  const float4* b2 = (const float4*)(B + (int64_t)r2*ldb);
  const float4* b3 = (const float4*)(B + (int64_t)r3*ldb);
  float4 acc = make_float4(0.f,0.f,0.f,0.f);
  int K4 = K>>2;
  for (int i=lane; i<K4; i+=64){
    float4 av = a4[i];
    float4 v0 = b0[i], v1 = b1[i], v2 = b2[i], v3 = b3[i];
    acc.x += av.x*v0.x + av.y*v0.y + av.z*v0.z + av.w*v0.w;
    acc.y += av.x*v1.x + av.y*v1.y + av.z*v1.z + av.w*v1.w;
    acc.z += av.x*v2.x + av.y*v2.y + av.z*v2.z + av.w*v2.w;
    acc.w += av.x*v3.x + av.y*v3.y + av.z*v3.z + av.w*v3.w;
  }
  acc = wsum4(acc);
  if (lane==0){
    float vals[4] = {acc.x, acc.y, acc.z, acc.w};
    #pragma unroll
    for (int j=0;j<4;j++){
      int n = n0+j;
      if (n<N){
        float v = vals[j];
        if (bias) v += bias[n];
        C[(int64_t)m*ldc + n] = v;
      }
    }
  }
}

// ---------------- GAT helpers ----------------
__global__ __launch_bounds__(256) void attcoef1_k(const float* __restrict__ h,
    const float* __restrict__ a_src, const float* __restrict__ a_dst,
    float* __restrict__ asrc, float* __restrict__ adst){
  int node = blockIdx.x*4 + (threadIdx.x>>6);
  if (node>=NN) return;
  int lane = threadIdx.x & 63;
  float4 hv = ((const float4*)h)[(int64_t)node*64 + lane];
  int head = lane >> 4;
  float4 as = ((const float4*)a_src)[head*16 + (lane&15)];
  float4 ad = ((const float4*)a_dst)[head*16 + (lane&15)];
  float ps = hv.x*as.x + hv.y*as.y + hv.z*as.z + hv.w*as.w;
  float pd = hv.x*ad.x + hv.y*ad.y + hv.z*ad.z + hv.w*ad.w;
  #pragma unroll
  for (int m=1;m<16;m<<=1){ ps += __shfl_xor(ps,m); pd += __shfl_xor(pd,m); }
  if ((lane&15)==0){ asrc[node*4+head]=ps; adst[node*4+head]=pd; }
}

__global__ __launch_bounds__(256) void attcoef2_k(const float* __restrict__ h,
    const float* __restrict__ a_src, const float* __restrict__ a_dst,
    float* __restrict__ asrc, float* __restrict__ adst){
  int node = blockIdx.x*4 + (threadIdx.x>>6);
  if (node>=NN) return;
  int lane = threadIdx.x & 63;
  float4 hv = ((const float4*)h)[(int64_t)node*64 + lane];
  float4 as = ((const float4*)a_src)[lane];
  float4 ad = ((const float4*)a_dst)[lane];
  float ps = hv.x*as.x + hv.y*as.y + hv.z*as.z + hv.w*as.w;
  float pd = hv.x*ad.x + hv.y*ad.y + hv.z*ad.z + hv.w*ad.w;
  ps = wsum(ps); pd = wsum(pd);
  if (lane==0){ asrc[node]=ps; adst[node]=pd; }
}

__global__ void edge_e1_k(const int* __restrict__ csr_src, const int* __restrict__ csr_dst,
                          const float* __restrict__ asrc, const float* __restrict__ adst,
                          float* __restrict__ ebuf){
  int p = blockIdx.x*256 + threadIdx.x;
  if (p>=ET) return;
  int s = csr_src[p], d = csr_dst[p];
  float4 a = ((const float4*)asrc)[s];
  float4 b = ((const float4*)adst)[d];
  float4 e;
  e.x = a.x+b.x; e.x = (e.x>=0.f)? e.x : 0.2f*e.x;
  e.y = a.y+b.y; e.y = (e.y>=0.f)? e.y : 0.2f*e.y;
  e.z = a.z+b.z; e.z = (e.z>=0.f)? e.z : 0.2f*e.z;
  e.w = a.w+b.w; e.w = (e.w>=0.f)? e.w : 0.2f*e.w;
  ((float4*)ebuf)[p] = e;
}

__global__ void edge_e2_k(const int* __restrict__ csr_src, const int* __restrict__ csr_dst,
                          const float* __restrict__ asrc, const float* __restrict__ adst,
                          float* __restrict__ ebuf){
  int p = blockIdx.x*256 + threadIdx.x;
  if (p>=ET) return;
  int s = csr_src[p], d = csr_dst[p];
  float e = asrc[s] + adst[d];
  e = (e>=0.f)? e : 0.2f*e;
  ebuf[p] = e;
}

// layer1: 4 heads of 64ch; lane covers channels 4*lane..4*lane+3 (head = lane>>4). +bias, elu.
__global__ __launch_bounds__(256) void agg1_k(const float* __restrict__ h, const float* __restrict__ ebuf,
    const int* __restrict__ rowstart, const int* __restrict__ csr_src,
    const float* __restrict__ bias, float* __restrict__ outp){
  int node = blockIdx.x*4 + (threadIdx.x>>6);
  if (node>=NN) return;
  int lane = threadIdx.x & 63;
  int rs = rowstart[node], re = rowstart[node+1];
  const float4* e4 = (const float4*)ebuf;
  float4 mx = make_float4(-INFINITY,-INFINITY,-INFINITY,-INFINITY);
  for (int p=rs+lane; p<re; p+=64){
    float4 e = e4[p];
    mx.x=fmaxf(mx.x,e.x); mx.y=fmaxf(mx.y,e.y); mx.z=fmaxf(mx.z,e.z); mx.w=fmaxf(mx.w,e.w);
  }
  mx = wmax4(mx);
  float4 sm = make_float4(0.f,0.f,0.f,0.f);
  for (int p=rs+lane; p<re; p+=64){
    float4 e = e4[p];
    sm.x += expf(e.x-mx.x); sm.y += expf(e.y-mx.y);
    sm.z += expf(e.z-mx.z); sm.w += expf(e.w-mx.w);
  }
  sm = wsum4(sm);
  int head = lane>>4;
  float m_h = head==0?mx.x:head==1?mx.y:head==2?mx.z:mx.w;
  float s_h = head==0?sm.x:head==1?sm.y:head==2?sm.z:sm.w;
  float dinv = 1.f/(s_h+1e-16f);
  const float4* h4 = (const float4*)h;
  float4 acc = make_float4(0.f,0.f,0.f,0.f);
  for (int p=rs; p<re; ++p){
    int s = csr_src[p];
    float w = expf(ebuf[p*4+head]-m_h)*dinv;
    float4 hv = h4[(int64_t)s*64 + lane];
    acc.x += w*hv.x; acc.y += w*hv.y; acc.z += w*hv.z; acc.w += w*hv.w;
  }
  float4 bb = ((const float4*)bias)[lane];
  float4 o;
  o.x = acc.x+bb.x; o.x = (o.x>0.f)? o.x : expm1f(o.x);
  o.y = acc.y+bb.y; o.y = (o.y>0.f)? o.y : expm1f(o.y);
  o.z = acc.z+bb.z; o.z = (o.z>0.f)? o.z : expm1f(o.z);
  o.w = acc.w+bb.w; o.w = (o.w>0.f)? o.w : expm1f(o.w);
  ((float4*)outp)[(int64_t)node*64 + lane] = o;
}

// layer2: single head over 256 ch. +bias, no act.
__global__ __launch_bounds__(256) void agg2_k(const float* __restrict__ h, const float* __restrict__ ebuf,
    const int* __restrict__ rowstart, const int* __restrict__ csr_src,
    const float* __restrict__ bias, float* __restrict__ outp){
  int node = blockIdx.x*4 + (threadIdx.x>>6);
  if (node>=NN) return;
  int lane = threadIdx.x & 63;
  int rs = rowstart[node], re = rowstart[node+1];
  float mx = -INFINITY;
  for (int p=rs+lane; p<re; p+=64) mx = fmaxf(mx, ebuf[p]);
  mx = wmax(mx);
  float sm = 0.f;
  for (int p=rs+lane; p<re; p+=64) sm += expf(ebuf[p]-mx);
  sm = wsum(sm);
  float dinv = 1.f/(sm+1e-16f);
  const float4* h4 = (const float4*)h;
  float4 acc = make_float4(0.f,0.f,0.f,0.f);
  for (int p=rs; p<re; ++p){
    int s = csr_src[p];
    float w = expf(ebuf[p]-mx)*dinv;
    float4 hv = h4[(int64_t)s*64 + lane];
    acc.x += w*hv.x; acc.y += w*hv.y; acc.z += w*hv.z; acc.w += w*hv.w;
  }
  float4 bb = ((const float4*)bias)[lane];
  float4 o = make_float4(acc.x+bb.x, acc.y+bb.y, acc.z+bb.z, acc.w+bb.w);
  ((float4*)outp)[(int64_t)node*64 + lane] = o;
}

// ---------------- small glue kernels ----------------
__global__ void gather_gsel_k(const float* __restrict__ out2, const int* __restrict__ cidx,
                              float* __restrict__ gsel){
  int idx = blockIdx.x*256 + threadIdx.x;
  if (idx >= NC*256) return;
  int i = idx >> 8, c = idx & 255;
  gsel[idx] = out2[(int64_t)cidx[i]*256 + c];
}

__global__ void build_fused_k(const float* __restrict__ bert, const float* __restrict__ gatc,
                              float* __restrict__ fused){
  int idx = blockIdx.x*256 + threadIdx.x;
  if (idx >= NC*1536) return;
  int i = idx / 1536, c = idx - i*1536;
  fused[idx] = (c<768)? bert[(int64_t)i*768 + c] : gatc[(int64_t)i*768 + (c-768)];
}

// LN over last dim 768 (optionally x = x1 + sigmoid(*gs)*x2), optional relu
__global__ __launch_bounds__(256) void ln_k(const float* __restrict__ x1, const float* __restrict__ x2,
    const float* __restrict__ gsptr, const float* __restrict__ g, const float* __restrict__ bb,
    float* __restrict__ outp, int relu){
  __shared__ float red[4];
  int row = blockIdx.x;
  int t = threadIdx.x;
  float gs = 0.f;
  if (x2) gs = 1.f/(1.f+expf(-gsptr[0]));
  const float* xr = x1 + (int64_t)row*768;
  float v0 = xr[t], v1 = xr[t+256], v2 = xr[t+512];
  if (x2){
    const float* x2r = x2 + (int64_t)row*768;
    v0 += gs*x2r[t]; v1 += gs*x2r[t+256]; v2 += gs*x2r[t+512];
  }
  int lane = t&63, wid = t>>6;
  float s = wsum(v0+v1+v2);
  if (lane==0) red[wid]=s;
  __syncthreads();
  float mean = (red[0]+red[1]+red[2]+red[3]) * (1.f/768.f);
  __syncthreads();
  float d0=v0-mean, d1=v1-mean, d2=v2-mean;
  float ss = wsum(d0*d0+d1*d1+d2*d2);
  if (lane==0) red[wid]=ss;
  __syncthreads();
  float var = (red[0]+red[1]+red[2]+red[3]) * (1.f/768.f);
  float rstd = rsqrtf(var + 1e-5f);
  float o0 = d0*rstd*g[t]+bb[t];
  float o1 = d1*rstd*g[t+256]+bb[t+256];
  float o2 = d2*rstd*g[t+512]+bb[t+512];
  if (relu){ o0=fmaxf(o0,0.f); o1=fmaxf(o1,0.f); o2=fmaxf(o2,0.f); }
  float* orow = outp + (int64_t)row*768;
  orow[t]=o0; orow[t+256]=o1; orow[t+512]=o2;
}

// softmax over last dim (NC=111) for rows of scores, in place
__global__ __launch_bounds__(256) void softmax_nc_k(float* __restrict__ sc, int rows){
  int row = blockIdx.x*4 + (threadIdx.x>>6);
  if (row>=rows) return;
  int lane = threadIdx.x & 63;
  float* r = sc + (int64_t)row*NC;
  float x0 = r[lane];
  float x1 = (lane+64<NC)? r[lane+64] : -INFINITY;
  float m = wmax(fmaxf(x0,x1));
  float p0 = expf(x0-m);
  float p1 = (lane+64<NC)? expf(x1-m) : 0.f;
  float s = wsum(p0+p1);
  float dinv = 1.f/s;
  r[lane] = p0*dinv;
  if (lane+64<NC) r[lane+64] = p1*dinv;
}

__global__ void mean_heads_k(const float* __restrict__ attn, float* __restrict__ outp){
  int64_t idx = (int64_t)blockIdx.x*256 + threadIdx.x;
  if (idx >= (int64_t)BB*SS*NC) return;
  int c = idx % NC;
  int64_t r = idx / NC;
  int s = r % SS;
  int b = r / SS;
  float acc = 0.f;
  #pragma unroll
  for (int h=0;h<8;h++)
    acc += attn[(((int64_t)(b*8+h)*SS)+s)*NC + c];
  outp[idx] = acc * 0.125f;
}

__global__ void sigmoid_k(const float* __restrict__ in, float* __restrict__ outp, int n,
                          const float* __restrict__ gsptr, float* __restrict__ gsout){
  int idx = blockIdx.x*256 + threadIdx.x;
  if (idx < n) outp[idx] = 1.f/(1.f+expf(-in[idx]));
  if (idx == 0) gsout[0] = 1.f/(1.f+expf(-gsptr[0]));
}

// softmax over S (axis=1) per (b,l), in place, with mask
__global__ __launch_bounds__(256) void laat_softmax_k(float* __restrict__ att, const int* __restrict__ mask){
  int idx = blockIdx.x*4 + (threadIdx.x>>6);
  if (idx >= BB*NL) return;
  int lane = threadIdx.x & 63;
  int b = idx / NL, l = idx - b*NL;
  float x[8];
  #pragma unroll
  for (int i=0;i<8;i++){
    int s = lane + i*64;
    int mk = mask[b*SS + s];
    x[i] = mk ? att[((int64_t)(b*SS+s))*NL + l] : -INFINITY;
  }
  float m = -INFINITY;
  #pragma unroll
  for (int i=0;i<8;i++) m = fmaxf(m, x[i]);
  m = wmax(m);
  float p[8]; float sm = 0.f;
  #pragma unroll
  for (int i=0;i<8;i++){ p[i] = expf(x[i]-m); sm += p[i]; }
  sm = wsum(sm);
  float dinv = 1.f/sm;
  #pragma unroll
  for (int i=0;i<8;i++){
    int s = lane + i*64;
    att[((int64_t)(b*SS+s))*NL + l] = p[i]*dinv;
  }
}

// label_reps[b,l,:] = sum_s w[b,s,l] * enr[b,s,:]  — 4-way s-parallel across waves
__global__ __launch_bounds__(256) void label_reps_k(const float* __restrict__ w,
    const float* __restrict__ enr, float* __restrict__ outp){
  __shared__ __align__(16) float part[4][768];
  int bl = blockIdx.x;
  int b = bl / NL, l = bl - b*NL;
  int t = threadIdx.x;
  int wid = t>>6, lane = t&63;
  const float* wb = w + (int64_t)b*SS*NL + l;
  const float* eb = enr + (int64_t)b*SS*768;
  float4 a0 = make_float4(0,0,0,0), a1 = a0, a2 = a0;
  for (int s=wid; s<SS; s+=4){
    float wv = wb[(int64_t)s*NL];
    const float4* row = (const float4*)(eb + (int64_t)s*768);
    float4 r0 = row[lane], r1 = row[lane+64], r2 = row[lane+128];
    a0.x += wv*r0.x; a0.y += wv*r0.y; a0.z += wv*r0.z; a0.w += wv*r0.w;
    a1.x += wv*r1.x; a1.y += wv*r1.y; a1.z += wv*r1.z; a1.w += wv*r1.w;
    a2.x += wv*r2.x; a2.y += wv*r2.y; a2.z += wv*r2.z; a2.w += wv*r2.w;
  }
  ((float4*)&part[wid][lane*4      ])[0] = a0;
  ((float4*)&part[wid][lane*4 + 256])[0] = a1;
  ((float4*)&part[wid][lane*4 + 512])[0] = a2;
  __syncthreads();
  float* o = outp + (int64_t)bl*768;
  #pragma unroll
  for (int q=0;q<3;q++){
    int ch = t + q*256;
    o[ch] = part[0][ch] + part[1][ch] + part[2][ch] + part[3][ch];
  }
}

__global__ __launch_bounds__(256) void logits_k(const float* __restrict__ lr,
    const float* __restrict__ low, const float* __restrict__ lob,
    const float* __restrict__ cs, const float* __restrict__ c2l,
    float* __restrict__ logits){
  int idx = blockIdx.x*4 + (threadIdx.x>>6);
  if (idx >= BB*NL) return;
  int lane = threadIdx.x & 63;
  int b = idx / NL, l = idx - b*NL;
  const float* r = lr + (int64_t)idx*768;
  float acc = 0.f;
  for (int c=lane;c<768;c+=64) acc += r[c]*low[c];
  for (int c=lane;c<NC;c+=64)  acc += cs[b*NC+c]*c2l[l*NC+c];
  acc = wsum(acc);
  if (lane==0) logits[idx] = acc + lob[0];
}

// ---------------- host ----------------
extern "C" void kernel_launch(void* const* d_in, const int* in_sizes, int n_in,
                              void* d_out, int out_size, void* d_ws, size_t ws_size,
                              hipStream_t stream)
{
  const float* hs    = (const float*)d_in[0];
  const int*   amask = (const int*)d_in[1];
  const float* bert  = (const float*)d_in[2];
  const float* gx    = (const float*)d_in[3];
  const int*   eidx  = (const int*)d_in[4];
  const int*   cidx  = (const int*)d_in[5];
  const float* w1    = (const float*)d_in[6];
  const float* as1   = (const float*)d_in[7];
  const float* ad1   = (const float*)d_in[8];
  const float* b1    = (const float*)d_in[9];
  const float* w2    = (const float*)d_in[10];
  const float* as2   = (const float*)d_in[11];
  const float* ad2   = (const float*)d_in[12];
  const float* b2    = (const float*)d_in[13];
  const float* gpw   = (const float*)d_in[14];
  const float* gpb   = (const float*)d_in[15];
  const float* fw    = (const float*)d_in[16];
  const float* fb    = (const float*)d_in[17];
  const float* flng  = (const float*)d_in[18];
  const float* flnb  = (const float*)d_in[19];
  const float* ipw   = (const float*)d_in[20];
  const float* ipb   = (const float*)d_in[21];
  const float* opw   = (const float*)d_in[22];
  const float* opb   = (const float*)d_in[23];
  const float* lng   = (const float*)d_in[24];
  const float* lnb   = (const float*)d_in[25];
  const float* chw   = (const float*)d_in[26];
  const float* chb   = (const float*)d_in[27];
  const float* lfw   = (const float*)d_in[28];
  const float* lsw   = (const float*)d_in[29];
  const float* low   = (const float*)d_in[30];
  const float* lob   = (const float*)d_in[31];
  const float* c2l   = (const float*)d_in[32];
  const float* gsc   = (const float*)d_in[33];
  float* out = (float*)d_out;

  // workspace layout
  int* deg      = (int*)d_ws;
  int* cursor   = deg + NN;
  int* rowstart = cursor + NN;
  int* csr_src  = rowstart + (NN+1);
  int* csr_dst  = csr_src + ET;
  int* incl     = csr_dst + ET;
  int* csum     = incl + NN;
  size_t iw = (size_t)NN*2 + (size_t)(NN+1) + (size_t)ET*2 + (size_t)NN + 64;
  float* fbase = (float*)d_ws + ((iw+3) & ~(size_t)3);
  float* ebuf  = fbase;                        // ET*4
  float* asrcb = ebuf  + (size_t)ET*4;         // NN*4
  float* adstb = asrcb + (size_t)NN*4;         // NN*4
  float* bufA  = adstb + (size_t)NN*4;         // NN*256
  float* bufB  = bufA  + (size_t)NN*256;       // NN*256
  float* gselb = bufB  + (size_t)NN*256;       // NC*256
  float* gatc  = gselb + (size_t)NC*256;       // NC*768
  float* fusedb= gatc  + (size_t)NC*HH;        // NC*1536
  float* kvb   = fusedb+ (size_t)NC*1536;      // NC*1536
  float* enhb  = kvb   + (size_t)NC*1536;      // NC*768
  // overlays (lifetimes disjoint with bufA/bufB graph contents)
  float* qb    = bufA;                                  // B*S*H
  float* scb   = bufA + (size_t)BB*SS*HH;               // B*8*S*NC
  float* ctxb  = scb  + (size_t)BB*8*SS*NC;             // B*S*H
  float* ctxt  = bufB;                                  // B*S*H
  float* enrb  = bufB + (size_t)BB*SS*HH;               // B*S*H
  float* Ub    = enrb + (size_t)BB*SS*HH;               // B*S*H
  float* attb  = Ub   + (size_t)BB*SS*HH;               // B*S*NL

  float* out_logits = out;
  float* out_cl = out + 400;
  float* out_cs = out + 1288;
  float* out_lr = out + 2176;
  float* out_aw = out + 309376;
  float* out_gs = out + 764032;

  hipMemsetAsync(deg,    0, sizeof(int)*NN, stream);
  hipMemsetAsync(cursor, 0, sizeof(int)*NN, stream);

  count_deg_k<<<(ET+255)/256,256,0,stream>>>(eidx, deg);
  int nch = (NN+1023)/1024;
  scan1_k<<<nch,1024,0,stream>>>(deg, incl, csum);
  scan2_k<<<1,64,0,stream>>>(csum, nch);
  scan3_k<<<(NN+255)/256,256,0,stream>>>(deg, incl, csum, rowstart);
  fill_csr_k<<<(ET+255)/256,256,0,stream>>>(eidx, rowstart, cursor, csr_src, csr_dst);

  auto gemm = [&](bool tb, const float* A, const float* Bm, const float* bias, float* C,
                  int M, int Nn, int K, int lda, int ldb, int ldc,
                  int nb, int nb2,
                  int64_t sA1,int64_t sA2,int64_t sB1,int64_t sB2,int64_t sC1,int64_t sC2,
                  float alpha, int act){
    dim3 g((Nn+63)/64, (M+127)/128, nb);
    if (tb) gemm_f32<true ><<<g,256,0,stream>>>(A,Bm,bias,C,M,Nn,K,lda,ldb,ldc,nb2,sA1,sA2,sB1,sB2,sC1,sC2,alpha,act);
    else    gemm_f32<false><<<g,256,0,stream>>>(A,Bm,bias,C,M,Nn,K,lda,ldb,ldc,nb2,sA1,sA2,sB1,sB2,sC1,sC2,alpha,act);
  };
  auto skinny = [&](const float* A, const float* Bm, const float* bias, float* C,
                    int M, int Nn, int K, int lda, int ldb, int ldc){
    int ngroups = (Nn+3)>>2;
    int waves = M*ngroups;
    skinny_tb_k<<<(waves+3)/4,256,0,stream>>>(A,Bm,bias,C,M,Nn,K,lda,ldb,ldc);
  };

  // ---- GAT layer 1 ----
  gemm(false, gx, w1, nullptr, bufA, NN, 256, 256, 256,256,256, 1,1, 0,0,0,0,0,0, 1.f, 0);
  attcoef1_k<<<(NN+3)/4,256,0,stream>>>(bufA, as1, ad1, asrcb, adstb);
  edge_e1_k<<<(ET+255)/256,256,0,stream>>>(csr_src, csr_dst, asrcb, adstb, ebuf);
  agg1_k<<<(NN+3)/4,256,0,stream>>>(bufA, ebuf, rowstart, csr_src, b1, bufB);
  // ---- GAT layer 2 ----
  gemm(false, bufB, w2, nullptr, bufA, NN, 256, 256, 256,256,256, 1,1, 0,0,0,0,0,0, 1.f, 0);
  attcoef2_k<<<(NN+3)/4,256,0,stream>>>(bufA, as2, ad2, asrcb, adstb);
  edge_e2_k<<<(ET+255)/256,256,0,stream>>>(csr_src, csr_dst, asrcb, adstb, ebuf);
  agg2_k<<<(NN+3)/4,256,0,stream>>>(bufA, ebuf, rowstart, csr_src, b2, bufB);
  // ---- concept path (all small-M: skinny) ----
  gather_gsel_k<<<(NC*256+255)/256,256,0,stream>>>(bufB, cidx, gselb);
  skinny(gselb, gpw, gpb, gatc, NC, HH, 256, 256,256,HH);
  build_fused_k<<<(NC*1536+255)/256,256,0,stream>>>(bert, gatc, fusedb);
  skinny(fusedb, fw, fb, enhb, NC, HH, 1536, 1536,1536,HH);
  ln_k<<<NC,256,0,stream>>>(enhb, nullptr, nullptr, flng, flnb, enhb, 1);
  // K,V for enhanced rows (same for all batches)
  skinny(enhb, ipw + (size_t)768*768, ipb+768, kvb, NC, 1536, 768, 768,768,1536);
  // Q
  gemm(true, hs, ipw, ipb, qb, BB*SS, HH, HH, 768,768,768, 1,1, 0,0,0,0,0,0, 1.f, 0);
  // scores[b,h]: (512x96)@(111x96)^T / sqrt(96)
  gemm(true, qb, kvb, nullptr, scb, SS, NC, 96, 768, 1536, NC, BB*8, 8,
       (int64_t)SS*HH, 96, 0, 96, (int64_t)8*SS*NC, (int64_t)SS*NC, 0.10206207261596577f, 0);
  softmax_nc_k<<<(BB*8*SS)/4,256,0,stream>>>(scb, BB*8*SS);
  mean_heads_k<<<(int)(((int64_t)BB*SS*NC+255)/256),256,0,stream>>>(scb, out_aw);
  // ctx[b,h]: (512x111)@(111x96)
  gemm(false, scb, kvb+768, nullptr, ctxb, SS, 96, NC, NC, 1536, HH, BB*8, 8,
       (int64_t)8*SS*NC, (int64_t)SS*NC, 0, 96, (int64_t)SS*HH, 96, 1.f, 0);
  gemm(true, ctxb, opw, opb, ctxt, BB*SS, HH, HH, 768,768,768, 1,1, 0,0,0,0,0,0, 1.f, 0);
  // concept logits / scores (M=8: skinny)
  skinny(hs, chw, chb, out_cl, BB, NC, HH, SS*HH, 768, NC);
  sigmoid_k<<<4,256,0,stream>>>(out_cl, out_cs, BB*NC, gsc, out_gs);
  // enriched = LN(hs + sigmoid(gs)*context)
  ln_k<<<BB*SS,256,0,stream>>>(hs, ctxt, gsc, lng, lnb, enrb, 0);
  // LAAT
  gemm(true, enrb, lfw, nullptr, Ub, BB*SS, HH, HH, 768,768,768, 1,1, 0,0,0,0,0,0, 1.f, 1);
  // att: M=4096, N=50 -> skinny (no bias)
  skinny(Ub, lsw, nullptr, attb, BB*SS, NL, HH, 768,768,NL);
  laat_softmax_k<<<(BB*NL+3)/4,256,0,stream>>>(attb, amask);
  label_reps_k<<<BB*NL,256,0,stream>>>(attb, enrb, out_lr);
  logits_k<<<(BB*NL+3)/4,256,0,stream>>>(out_lr, low, lob, out_cs, c2l, out_logits);
}

// Round 6
// 1175.629 us; speedup vs baseline: 1.7146x; 1.5425x over previous
//
#include <hip/hip_runtime.h>
#include <math.h>
#include <stdint.h>

static constexpr int NN = 50000;      // graph nodes
static constexpr int EE = 800000;     // edges (no self loops)
static constexpr int ET = EE + NN;    // edges + self loops
static constexpr int BB = 8;
static constexpr int SS = 512;
static constexpr int HH = 768;
static constexpr int NC = 111;
static constexpr int NL = 50;

#define DINL __device__ __forceinline__

typedef __attribute__((ext_vector_type(8))) short bf16x8;
typedef __attribute__((ext_vector_type(4))) float f32x4;

DINL float wsum(float v){
  #pragma unroll
  for (int m=1;m<64;m<<=1) v += __shfl_xor(v, m);
  return v;
}
DINL float wmax(float v){
  #pragma unroll
  for (int m=1;m<64;m<<=1) v = fmaxf(v, __shfl_xor(v, m));
  return v;
}
DINL float4 wsum4(float4 v){
  #pragma unroll
  for (int m=1;m<64;m<<=1){
    v.x += __shfl_xor(v.x,m); v.y += __shfl_xor(v.y,m);
    v.z += __shfl_xor(v.z,m); v.w += __shfl_xor(v.w,m);
  }
  return v;
}
DINL float4 wmax4(float4 v){
  #pragma unroll
  for (int m=1;m<64;m<<=1){
    v.x=fmaxf(v.x,__shfl_xor(v.x,m)); v.y=fmaxf(v.y,__shfl_xor(v.y,m));
    v.z=fmaxf(v.z,__shfl_xor(v.z,m)); v.w=fmaxf(v.w,__shfl_xor(v.w,m));
  }
  return v;
}

// ---------------- CSR build ----------------
__global__ void count_deg_k(const int* __restrict__ eidx, int* __restrict__ deg){
  int i = blockIdx.x*256 + threadIdx.x;
  if (i>=ET) return;
  int d = (i<EE)? eidx[EE + i] : (i - EE);
  atomicAdd(&deg[d], 1);
}

__global__ __launch_bounds__(1024) void scan1_k(const int* __restrict__ deg,
                                                int* __restrict__ incl, int* __restrict__ csum){
  __shared__ int sh[1024];
  int tid = threadIdx.x;
  int i = blockIdx.x*1024 + tid;
  int v = (i<NN)? deg[i] : 0;
  sh[tid] = v;
  __syncthreads();
  for (int off=1; off<1024; off<<=1){
    int t = (tid>=off)? sh[tid-off] : 0;
    __syncthreads();
    sh[tid] += t;
    __syncthreads();
  }
  if (i<NN) incl[i] = sh[tid];
  if (tid==1023) csum[blockIdx.x] = sh[1023];
}

__global__ void scan2_k(int* __restrict__ csum, int nch){
  if (threadIdx.x==0 && blockIdx.x==0){
    int run = 0;
    for (int i=0;i<nch;i++){ int v = csum[i]; csum[i] = run; run += v; }
  }
}

__global__ void scan3_k(const int* __restrict__ deg, const int* __restrict__ incl,
                        const int* __restrict__ csum, int* __restrict__ rowstart){
  int i = blockIdx.x*256 + threadIdx.x;
  if (i>=NN) return;
  int ex = csum[i>>10] + incl[i] - deg[i];
  rowstart[i] = ex;
  if (i==NN-1) rowstart[NN] = ex + deg[i];
}

__global__ void fill_csr_k(const int* __restrict__ eidx, const int* __restrict__ rowstart,
                           int* __restrict__ cursor, int* __restrict__ csr_src, int* __restrict__ csr_dst){
  int i = blockIdx.x*256 + threadIdx.x;
  if (i>=ET) return;
  int s, d;
  if (i<EE){ s = eidx[i]; d = eidx[EE+i]; } else { s = i-EE; d = i-EE; }
  int pos = rowstart[d] + atomicAdd(&cursor[d], 1);
  csr_src[pos] = s; csr_dst[pos] = d;
}

// ---------------- bf16 split helpers ----------------
DINL uint bf16_rne(float x){
  uint u = __float_as_uint(x);
  return (u + 0x7FFFu + ((u>>16)&1u)) >> 16;
}
DINL void split8(const float4 v0, const float4 v1, uint4& ph, uint4& pl){
  float xs[8] = {v0.x,v0.y,v0.z,v0.w,v1.x,v1.y,v1.z,v1.w};
  uint hh[8], ll[8];
  #pragma unroll
  for (int i=0;i<8;i++){
    uint hb = bf16_rne(xs[i]);
    float hf = __uint_as_float(hb<<16);
    float lo = xs[i] - hf;
    hh[i] = hb; ll[i] = bf16_rne(lo);
  }
  ph = make_uint4(hh[0]|(hh[1]<<16), hh[2]|(hh[3]<<16), hh[4]|(hh[5]<<16), hh[6]|(hh[7]<<16));
  pl = make_uint4(ll[0]|(ll[1]<<16), ll[2]|(ll[3]<<16), ll[4]|(ll[5]<<16), ll[6]|(ll[7]<<16));
}

// split f32 [n] -> bf16 hi/lo (row-major preserved)
__global__ void split_k(const float* __restrict__ in, ushort* __restrict__ hi,
                        ushort* __restrict__ lo, int n){
  int i = blockIdx.x*256 + threadIdx.x;
  if (i>=n) return;
  float x = in[i];
  uint hb = bf16_rne(x);
  float hf = __uint_as_float(hb<<16);
  hi[i] = (ushort)hb;
  lo[i] = (ushort)bf16_rne(x - hf);
}

// in [R][C] (K x N) -> out [C][R] (N x K), split
__global__ void split_t_k(const float* __restrict__ in, ushort* __restrict__ hi,
                          ushort* __restrict__ lo, int R, int C){
  int i = blockIdx.x*256 + threadIdx.x;
  if (i>=R*C) return;
  int n = i / R, k = i - n*R;
  float x = in[k*C + n];
  uint hb = bf16_rne(x);
  float hf = __uint_as_float(hb<<16);
  hi[i] = (ushort)hb;
  lo[i] = (ushort)bf16_rne(x - hf);
}

// ---------------- bf16x3 MFMA GEMM ----------------
// C[M,N] = act(alpha*(A[M,K] . B[N,K]^T) + bias[n]); A f32 (split in-kernel),
// B pre-split bf16 hi/lo [N][K]. Tile 128x64, BK=64, 256 thr (4 waves, 2Mx2N).
// Requires N%64==0, K%64==0.
__global__ __launch_bounds__(256) void gemm_mfma3(
    const float* __restrict__ A, const ushort* __restrict__ Bh, const ushort* __restrict__ Bl,
    const float* __restrict__ bias, float* __restrict__ C,
    int M, int N, int K, float alpha, int act)
{
  __shared__ __align__(16) ushort As[2][128*64];
  __shared__ __align__(16) ushort Bs[2][64*64];
  const int tid = threadIdx.x;
  const int lane = tid & 63, wid = tid >> 6;
  const int wm = wid >> 1, wn = wid & 1;
  const int m0 = blockIdx.y*128, n0 = blockIdx.x*64;
  f32x4 acc[4][2];
  #pragma unroll
  for (int i=0;i<4;i++)
    #pragma unroll
    for (int j=0;j<2;j++) acc[i][j] = (f32x4){0.f,0.f,0.f,0.f};

  const int nkt = K >> 6;
  for (int kt=0; kt<nkt; ++kt){
    // stage A (f32 -> hi/lo planes)
    #pragma unroll
    for (int q=0;q<4;q++){
      int idx = q*256 + tid;       // 0..1023
      int row = idx >> 3;          // 0..127
      int g8  = idx & 7;           // group of 8 floats
      int rowg = m0 + row; if (rowg >= M) rowg = M-1;
      const float* src = A + (int64_t)rowg*K + (kt<<6) + g8*8;
      float4 v0 = ((const float4*)src)[0];
      float4 v1 = ((const float4*)src)[1];
      uint4 ph, pl;
      split8(v0, v1, ph, pl);
      int off = row*64 + ((g8*8) ^ ((row&7)<<3));
      *(uint4*)&As[0][off] = ph;
      *(uint4*)&As[1][off] = pl;
    }
    // stage B (already bf16 hi/lo)
    #pragma unroll
    for (int q=0;q<4;q++){
      int idx = q*256 + tid;       // 0..1023
      int plane = idx >> 9;
      int rem = idx & 511;
      int row = rem >> 3;          // 0..63
      int g8 = rem & 7;
      const ushort* src = (plane ? Bl : Bh) + (int64_t)(n0+row)*K + (kt<<6) + g8*8;
      uint4 v = *(const uint4*)src;
      int off = row*64 + ((g8*8) ^ ((row&7)<<3));
      *(uint4*)&Bs[plane][off] = v;
    }
    __syncthreads();
    #pragma unroll
    for (int ks=0; ks<2; ks++){
      const int kswz = ks*32 + ((lane>>4)<<3);
      bf16x8 ah[4], al[4], bh[2], bl[2];
      #pragma unroll
      for (int mi=0;mi<4;mi++){
        int r = wm*64 + mi*16 + (lane&15);
        int off = r*64 + (kswz ^ ((r&7)<<3));
        ah[mi] = *(const bf16x8*)&As[0][off];
        al[mi] = *(const bf16x8*)&As[1][off];
      }
      #pragma unroll
      for (int nj=0;nj<2;nj++){
        int r = wn*32 + nj*16 + (lane&15);
        int off = r*64 + (kswz ^ ((r&7)<<3));
        bh[nj] = *(const bf16x8*)&Bs[0][off];
        bl[nj] = *(const bf16x8*)&Bs[1][off];
      }
      #pragma unroll
      for (int mi=0;mi<4;mi++)
        #pragma unroll
        for (int nj=0;nj<2;nj++){
          acc[mi][nj] = __builtin_amdgcn_mfma_f32_16x16x32_bf16(ah[mi], bh[nj], acc[mi][nj], 0,0,0);
          acc[mi][nj] = __builtin_amdgcn_mfma_f32_16x16x32_bf16(ah[mi], bl[nj], acc[mi][nj], 0,0,0);
          acc[mi][nj] = __builtin_amdgcn_mfma_f32_16x16x32_bf16(al[mi], bh[nj], acc[mi][nj], 0,0,0);
        }
    }
    __syncthreads();
  }
  // epilogue: C row = (lane>>4)*4 + j, col = lane&15
  const int crow = (lane>>4)*4, ccol = lane&15;
  #pragma unroll
  for (int nj=0;nj<2;nj++){
    int n = n0 + wn*32 + nj*16 + ccol;
    float bv = bias ? bias[n] : 0.f;
    #pragma unroll
    for (int mi=0;mi<4;mi++){
      #pragma unroll
      for (int j=0;j<4;j++){
        int m = m0 + wm*64 + mi*16 + crow + j;
        if (m < M){
          float v = acc[mi][nj][j]*alpha + bv;
          if (act==1) v = tanhf(v);
          C[(int64_t)m*N + n] = v;
        }
      }
    }
  }
}

// ---------------- generic f32 GEMM (128x64 tile, 8x4 per-thread) ----------------
template<bool TB>
__global__ __launch_bounds__(256) void gemm_f32(
    const float* __restrict__ A, const float* __restrict__ Bm,
    const float* __restrict__ bias, float* __restrict__ C,
    int M, int N, int K, int lda, int ldb, int ldc,
    int nb2,
    int64_t sA1, int64_t sA2, int64_t sB1, int64_t sB2, int64_t sC1, int64_t sC2,
    float alpha, int act)
{
  int z = blockIdx.z;
  int z1 = z / nb2, z2 = z - z1*nb2;
  A  += z1*sA1 + z2*sA2;
  Bm += z1*sB1 + z2*sB2;
  C  += z1*sC1 + z2*sC2;
  __shared__ __align__(16) float sA[16][132];
  __shared__ __align__(16) float sB[16][68];
  const int tid = threadIdx.x;
  const int m0 = blockIdx.y*128, n0 = blockIdx.x*64;
  const int tx = tid & 15, ty = tid >> 4;
  float acc[8][4] = {};
  for (int k0=0; k0<K; k0+=16){
    {
      int kk = tid & 15, mm = tid >> 4;
      #pragma unroll
      for (int r=0;r<8;r++){
        int m = m0 + mm + r*16, k = k0 + kk;
        float v = 0.f;
        if (m<M && k<K) v = A[(int64_t)m*lda + k];
        sA[kk][mm + r*16] = v;
      }
    }
    if (!TB){
      int nn = tid & 63, kb = tid >> 6;
      #pragma unroll
      for (int r=0;r<4;r++){
        int k = k0 + kb + r*4, n = n0 + nn;
        float v=0.f;
        if (k<K && n<N) v = Bm[(int64_t)k*ldb + n];
        sB[kb + r*4][nn] = v;
      }
    } else {
      int kk = tid & 15, nn = tid >> 4;
      #pragma unroll
      for (int r=0;r<4;r++){
        int n = n0 + nn + r*16, k = k0 + kk;
        float v=0.f;
        if (n<N && k<K) v = Bm[(int64_t)n*ldb + k];
        sB[kk][nn + r*16] = v;
      }
    }
    __syncthreads();
    #pragma unroll
    for (int k=0;k<16;k++){
      float4 a0 = *(const float4*)&sA[k][ty*8];
      float4 a1 = *(const float4*)&sA[k][ty*8+4];
      float4 b  = *(const float4*)&sB[k][tx*4];
      float av[8] = {a0.x,a0.y,a0.z,a0.w,a1.x,a1.y,a1.z,a1.w};
      float bv[4] = {b.x,b.y,b.z,b.w};
      #pragma unroll
      for (int i=0;i<8;i++)
        #pragma unroll
        for (int j=0;j<4;j++)
          acc[i][j] += av[i]*bv[j];
    }
    __syncthreads();
  }
  #pragma unroll
  for (int i=0;i<8;i++){
    int m = m0 + ty*8 + i;
    if (m>=M) continue;
    #pragma unroll
    for (int j=0;j<4;j++){
      int n = n0 + tx*4 + j;
      if (n>=N) continue;
      float v = acc[i][j]*alpha;
      if (bias) v += bias[n];
      if (act==1) v = tanhf(v);
      C[(int64_t)m*ldc + n] = v;
    }
  }
}

// ---------------- skinny GEMM: C[M,N] = A[M,K] @ B[N,K]^T + bias ----------------
__global__ __launch_bounds__(256) void skinny_tb_k(
    const float* __restrict__ A, const float* __restrict__ B,
    const float* __restrict__ bias, float* __restrict__ C,
    int M, int N, int K, int lda, int ldb, int ldc)
{
  int ngroups = (N+3)>>2;
  int w = blockIdx.x*4 + (threadIdx.x>>6);
  if (w >= M*ngroups) return;
  int lane = threadIdx.x & 63;
  int m = w / ngroups, ng = w - m*ngroups;
  int n0 = ng*4;
  const float4* a4 = (const float4*)(A + (int64_t)m*lda);
  int r0 = n0, r1 = (n0+1<N)? n0+1 : N-1, r2 = (n0+2<N)? n0+2 : N-1, r3 = (n0+3<N)? n0+3 : N-1;
  const float4* b0 = (const float4*)(B + (int64_t)r0*ldb);
  const float4* b1 = (const float4*)(B + (int64_t)r1*ldb);
  const float4* b2 = (const float4*)(B + (int64_t)r2*ldb);
  const float4* b3 = (const float4*)(B + (int64_t)r3*ldb);
  float4 acc = make_float4(0.f,0.f,0.f,0.f);
  int K4 = K>>2;
  for (int i=lane; i<K4; i+=64){
    float4 av = a4[i];
    float4 v0 = b0[i], v1 = b1[i], v2 = b2[i], v3 = b3[i];
    acc.x += av.x*v0.x + av.y*v0.y + av.z*v0.z + av.w*v0.w;
    acc.y += av.x*v1.x + av.y*v1.y + av.z*v1.z + av.w*v1.w;
    acc.z += av.x*v2.x + av.y*v2.y + av.z*v2.z + av.w*v2.w;
    acc.w += av.x*v3.x + av.y*v3.y + av.z*v3.z + av.w*v3.w;
  }
  acc = wsum4(acc);
  if (lane==0){
    float vals[4] = {acc.x, acc.y, acc.z, acc.w};
    #pragma unroll
    for (int j=0;j<4;j++){
      int n = n0+j;
      if (n<N){
        float v = vals[j];
        if (bias) v += bias[n];
        C[(int64_t)m*ldc + n] = v;
      }
    }
  }
}

// ---------------- GAT helpers ----------------
__global__ __launch_bounds__(256) void attcoef1_k(const float* __restrict__ h,
    const float* __restrict__ a_src, const float* __restrict__ a_dst,
    float* __restrict__ asrc, float* __restrict__ adst){
  int node = blockIdx.x*4 + (threadIdx.x>>6);
  if (node>=NN) return;
  int lane = threadIdx.x & 63;
  float4 hv = ((const float4*)h)[(int64_t)node*64 + lane];
  int head = lane >> 4;
  float4 as = ((const float4*)a_src)[head*16 + (lane&15)];
  float4 ad = ((const float4*)a_dst)[head*16 + (lane&15)];
  float ps = hv.x*as.x + hv.y*as.y + hv.z*as.z + hv.w*as.w;
  float pd = hv.x*ad.x + hv.y*ad.y + hv.z*ad.z + hv.w*ad.w;
  #pragma unroll
  for (int m=1;m<16;m<<=1){ ps += __shfl_xor(ps,m); pd += __shfl_xor(pd,m); }
  if ((lane&15)==0){ asrc[node*4+head]=ps; adst[node*4+head]=pd; }
}

__global__ __launch_bounds__(256) void attcoef2_k(const float* __restrict__ h,
    const float* __restrict__ a_src, const float* __restrict__ a_dst,
    float* __restrict__ asrc, float* __restrict__ adst){
  int node = blockIdx.x*4 + (threadIdx.x>>6);
  if (node>=NN) return;
  int lane = threadIdx.x & 63;
  float4 hv = ((const float4*)h)[(int64_t)node*64 + lane];
  float4 as = ((const float4*)a_src)[lane];
  float4 ad = ((const float4*)a_dst)[lane];
  float ps = hv.x*as.x + hv.y*as.y + hv.z*as.z + hv.w*as.w;
  float pd = hv.x*ad.x + hv.y*ad.y + hv.z*ad.z + hv.w*ad.w;
  ps = wsum(ps); pd = wsum(pd);
  if (lane==0){ asrc[node]=ps; adst[node]=pd; }
}

__global__ void edge_e1_k(const int* __restrict__ csr_src, const int* __restrict__ csr_dst,
                          const float* __restrict__ asrc, const float* __restrict__ adst,
                          float* __restrict__ ebuf){
  int p = blockIdx.x*256 + threadIdx.x;
  if (p>=ET) return;
  int s = csr_src[p], d = csr_dst[p];
  float4 a = ((const float4*)asrc)[s];
  float4 b = ((const float4*)adst)[d];
  float4 e;
  e.x = a.x+b.x; e.x = (e.x>=0.f)? e.x : 0.2f*e.x;
  e.y = a.y+b.y; e.y = (e.y>=0.f)? e.y : 0.2f*e.y;
  e.z = a.z+b.z; e.z = (e.z>=0.f)? e.z : 0.2f*e.z;
  e.w = a.w+b.w; e.w = (e.w>=0.f)? e.w : 0.2f*e.w;
  ((float4*)ebuf)[p] = e;
}

__global__ void edge_e2_k(const int* __restrict__ csr_src, const int* __restrict__ csr_dst,
                          const float* __restrict__ asrc, const float* __restrict__ adst,
                          float* __restrict__ ebuf){
  int p = blockIdx.x*256 + threadIdx.x;
  if (p>=ET) return;
  int s = csr_src[p], d = csr_dst[p];
  float e = asrc[s] + adst[d];
  e = (e>=0.f)? e : 0.2f*e;
  ebuf[p] = e;
}

__global__ __launch_bounds__(256) void agg1_k(const float* __restrict__ h, const float* __restrict__ ebuf,
    const int* __restrict__ rowstart, const int* __restrict__ csr_src,
    const float* __restrict__ bias, float* __restrict__ outp){
  int node = blockIdx.x*4 + (threadIdx.x>>6);
  if (node>=NN) return;
  int lane = threadIdx.x & 63;
  int rs = rowstart[node], re = rowstart[node+1];
  const float4* e4 = (const float4*)ebuf;
  float4 mx = make_float4(-INFINITY,-INFINITY,-INFINITY,-INFINITY);
  for (int p=rs+lane; p<re; p+=64){
    float4 e = e4[p];
    mx.x=fmaxf(mx.x,e.x); mx.y=fmaxf(mx.y,e.y); mx.z=fmaxf(mx.z,e.z); mx.w=fmaxf(mx.w,e.w);
  }
  mx = wmax4(mx);
  float4 sm = make_float4(0.f,0.f,0.f,0.f);
  for (int p=rs+lane; p<re; p+=64){
    float4 e = e4[p];
    sm.x += expf(e.x-mx.x); sm.y += expf(e.y-mx.y);
    sm.z += expf(e.z-mx.z); sm.w += expf(e.w-mx.w);
  }
  sm = wsum4(sm);
  int head = lane>>4;
  float m_h = head==0?mx.x:head==1?mx.y:head==2?mx.z:mx.w;
  float s_h = head==0?sm.x:head==1?sm.y:head==2?sm.z:sm.w;
  float dinv = 1.f/(s_h+1e-16f);
  const float4* h4 = (const float4*)h;
  float4 acc = make_float4(0.f,0.f,0.f,0.f);
  for (int p=rs; p<re; ++p){
    int s = csr_src[p];
    float w = expf(ebuf[p*4+head]-m_h)*dinv;
    float4 hv = h4[(int64_t)s*64 + lane];
    acc.x += w*hv.x; acc.y += w*hv.y; acc.z += w*hv.z; acc.w += w*hv.w;
  }
  float4 bb = ((const float4*)bias)[lane];
  float4 o;
  o.x = acc.x+bb.x; o.x = (o.x>0.f)? o.x : expm1f(o.x);
  o.y = acc.y+bb.y; o.y = (o.y>0.f)? o.y : expm1f(o.y);
  o.z = acc.z+bb.z; o.z = (o.z>0.f)? o.z : expm1f(o.z);
  o.w = acc.w+bb.w; o.w = (o.w>0.f)? o.w : expm1f(o.w);
  ((float4*)outp)[(int64_t)node*64 + lane] = o;
}

__global__ __launch_bounds__(256) void agg2_k(const float* __restrict__ h, const float* __restrict__ ebuf,
    const int* __restrict__ rowstart, const int* __restrict__ csr_src,
    const float* __restrict__ bias, float* __restrict__ outp){
  int node = blockIdx.x*4 + (threadIdx.x>>6);
  if (node>=NN) return;
  int lane = threadIdx.x & 63;
  int rs = rowstart[node], re = rowstart[node+1];
  float mx = -INFINITY;
  for (int p=rs+lane; p<re; p+=64) mx = fmaxf(mx, ebuf[p]);
  mx = wmax(mx);
  float sm = 0.f;
  for (int p=rs+lane; p<re; p+=64) sm += expf(ebuf[p]-mx);
  sm = wsum(sm);
  float dinv = 1.f/(sm+1e-16f);
  const float4* h4 = (const float4*)h;
  float4 acc = make_float4(0.f,0.f,0.f,0.f);
  for (int p=rs; p<re; ++p){
    int s = csr_src[p];
    float w = expf(ebuf[p]-mx)*dinv;
    float4 hv = h4[(int64_t)s*64 + lane];
    acc.x += w*hv.x; acc.y += w*hv.y; acc.z += w*hv.z; acc.w += w*hv.w;
  }
  float4 bb = ((const float4*)bias)[lane];
  float4 o = make_float4(acc.x+bb.x, acc.y+bb.y, acc.z+bb.z, acc.w+bb.w);
  ((float4*)outp)[(int64_t)node*64 + lane] = o;
}

// ---------------- small glue kernels ----------------
__global__ void gather_gsel_k(const float* __restrict__ out2, const int* __restrict__ cidx,
                              float* __restrict__ gsel){
  int idx = blockIdx.x*256 + threadIdx.x;
  if (idx >= NC*256) return;
  int i = idx >> 8, c = idx & 255;
  gsel[idx] = out2[(int64_t)cidx[i]*256 + c];
}

__global__ void build_fused_k(const float* __restrict__ bert, const float* __restrict__ gatc,
                              float* __restrict__ fused){
  int idx = blockIdx.x*256 + threadIdx.x;
  if (idx >= NC*1536) return;
  int i = idx / 1536, c = idx - i*1536;
  fused[idx] = (c<768)? bert[(int64_t)i*768 + c] : gatc[(int64_t)i*768 + (c-768)];
}

__global__ __launch_bounds__(256) void ln_k(const float* __restrict__ x1, const float* __restrict__ x2,
    const float* __restrict__ gsptr, const float* __restrict__ g, const float* __restrict__ bb,
    float* __restrict__ outp, int relu){
  __shared__ float red[4];
  int row = blockIdx.x;
  int t = threadIdx.x;
  float gs = 0.f;
  if (x2) gs = 1.f/(1.f+expf(-gsptr[0]));
  const float* xr = x1 + (int64_t)row*768;
  float v0 = xr[t], v1 = xr[t+256], v2 = xr[t+512];
  if (x2){
    const float* x2r = x2 + (int64_t)row*768;
    v0 += gs*x2r[t]; v1 += gs*x2r[t+256]; v2 += gs*x2r[t+512];
  }
  int lane = t&63, wid = t>>6;
  float s = wsum(v0+v1+v2);
  if (lane==0) red[wid]=s;
  __syncthreads();
  float mean = (red[0]+red[1]+red[2]+red[3]) * (1.f/768.f);
  __syncthreads();
  float d0=v0-mean, d1=v1-mean, d2=v2-mean;
  float ss = wsum(d0*d0+d1*d1+d2*d2);
  if (lane==0) red[wid]=ss;
  __syncthreads();
  float var = (red[0]+red[1]+red[2]+red[3]) * (1.f/768.f);
  float rstd = rsqrtf(var + 1e-5f);
  float o0 = d0*rstd*g[t]+bb[t];
  float o1 = d1*rstd*g[t+256]+bb[t+256];
  float o2 = d2*rstd*g[t+512]+bb[t+512];
  if (relu){ o0=fmaxf(o0,0.f); o1=fmaxf(o1,0.f); o2=fmaxf(o2,0.f); }
  float* orow = outp + (int64_t)row*768;
  orow[t]=o0; orow[t+256]=o1; orow[t+512]=o2;
}

__global__ __launch_bounds__(256) void softmax_nc_k(float* __restrict__ sc, int rows){
  int row = blockIdx.x*4 + (threadIdx.x>>6);
  if (row>=rows) return;
  int lane = threadIdx.x & 63;
  float* r = sc + (int64_t)row*NC;
  float x0 = r[lane];
  float x1 = (lane+64<NC)? r[lane+64] : -INFINITY;
  float m = wmax(fmaxf(x0,x1));
  float p0 = expf(x0-m);
  float p1 = (lane+64<NC)? expf(x1-m) : 0.f;
  float s = wsum(p0+p1);
  float dinv = 1.f/s;
  r[lane] = p0*dinv;
  if (lane+64<NC) r[lane+64] = p1*dinv;
}

__global__ void mean_heads_k(const float* __restrict__ attn, float* __restrict__ outp){
  int64_t idx = (int64_t)blockIdx.x*256 + threadIdx.x;
  if (idx >= (int64_t)BB*SS*NC) return;
  int c = idx % NC;
  int64_t r = idx / NC;
  int s = r % SS;
  int b = r / SS;
  float acc = 0.f;
  #pragma unroll
  for (int h=0;h<8;h++)
    acc += attn[(((int64_t)(b*8+h)*SS)+s)*NC + c];
  outp[idx] = acc * 0.125f;
}

__global__ void sigmoid_k(const float* __restrict__ in, float* __restrict__ outp, int n,
                          const float* __restrict__ gsptr, float* __restrict__ gsout){
  int idx = blockIdx.x*256 + threadIdx.x;
  if (idx < n) outp[idx] = 1.f/(1.f+expf(-in[idx]));
  if (idx == 0) gsout[0] = 1.f/(1.f+expf(-gsptr[0]));
}

__global__ __launch_bounds__(256) void laat_softmax_k(float* __restrict__ att, const int* __restrict__ mask){
  int idx = blockIdx.x*4 + (threadIdx.x>>6);
  if (idx >= BB*NL) return;
  int lane = threadIdx.x & 63;
  int b = idx / NL, l = idx - b*NL;
  float x[8];
  #pragma unroll
  for (int i=0;i<8;i++){
    int s = lane + i*64;
    int mk = mask[b*SS + s];
    x[i] = mk ? att[((int64_t)(b*SS+s))*NL + l] : -INFINITY;
  }
  float m = -INFINITY;
  #pragma unroll
  for (int i=0;i<8;i++) m = fmaxf(m, x[i]);
  m = wmax(m);
  float p[8]; float sm = 0.f;
  #pragma unroll
  for (int i=0;i<8;i++){ p[i] = expf(x[i]-m); sm += p[i]; }
  sm = wsum(sm);
  float dinv = 1.f/sm;
  #pragma unroll
  for (int i=0;i<8;i++){
    int s = lane + i*64;
    att[((int64_t)(b*SS+s))*NL + l] = p[i]*dinv;
  }
}

__global__ __launch_bounds__(256) void label_reps_k(const float* __restrict__ w,
    const float* __restrict__ enr, float* __restrict__ outp){
  __shared__ __align__(16) float part[4][768];
  int bl = blockIdx.x;
  int b = bl / NL, l = bl - b*NL;
  int t = threadIdx.x;
  int wid = t>>6, lane = t&63;
  const float* wb = w + (int64_t)b*SS*NL + l;
  const float* eb = enr + (int64_t)b*SS*768;
  float4 a0 = make_float4(0,0,0,0), a1 = a0, a2 = a0;
  for (int s=wid; s<SS; s+=4){
    float wv = wb[(int64_t)s*NL];
    const float4* row = (const float4*)(eb + (int64_t)s*768);
    float4 r0 = row[lane], r1 = row[lane+64], r2 = row[lane+128];
    a0.x += wv*r0.x; a0.y += wv*r0.y; a0.z += wv*r0.z; a0.w += wv*r0.w;
    a1.x += wv*r1.x; a1.y += wv*r1.y; a1.z += wv*r1.z; a1.w += wv*r1.w;
    a2.x += wv*r2.x; a2.y += wv*r2.y; a2.z += wv*r2.z; a2.w += wv*r2.w;
  }
  ((float4*)&part[wid][lane*4      ])[0] = a0;
  ((float4*)&part[wid][lane*4 + 256])[0] = a1;
  ((float4*)&part[wid][lane*4 + 512])[0] = a2;
  __syncthreads();
  float* o = outp + (int64_t)bl*768;
  #pragma unroll
  for (int q=0;q<3;q++){
    int ch = t + q*256;
    o[ch] = part[0][ch] + part[1][ch] + part[2][ch] + part[3][ch];
  }
}

__global__ __launch_bounds__(256) void logits_k(const float* __restrict__ lr,
    const float* __restrict__ low, const float* __restrict__ lob,
    const float* __restrict__ cs, const float* __restrict__ c2l,
    float* __restrict__ logits){
  int idx = blockIdx.x*4 + (threadIdx.x>>6);
  if (idx >= BB*NL) return;
  int lane = threadIdx.x & 63;
  int b = idx / NL, l = idx - b*NL;
  const float* r = lr + (int64_t)idx*768;
  float acc = 0.f;
  for (int c=lane;c<768;c+=64) acc += r[c]*low[c];
  for (int c=lane;c<NC;c+=64)  acc += cs[b*NC+c]*c2l[l*NC+c];
  acc = wsum(acc);
  if (lane==0) logits[idx] = acc + lob[0];
}

// ---------------- host ----------------
extern "C" void kernel_launch(void* const* d_in, const int* in_sizes, int n_in,
                              void* d_out, int out_size, void* d_ws, size_t ws_size,
                              hipStream_t stream)
{
  const float* hs    = (const float*)d_in[0];
  const int*   amask = (const int*)d_in[1];
  const float* bert  = (const float*)d_in[2];
  const float* gx    = (const float*)d_in[3];
  const int*   eidx  = (const int*)d_in[4];
  const int*   cidx  = (const int*)d_in[5];
  const float* w1    = (const float*)d_in[6];
  const float* as1   = (const float*)d_in[7];
  const float* ad1   = (const float*)d_in[8];
  const float* b1    = (const float*)d_in[9];
  const float* w2    = (const float*)d_in[10];
  const float* as2   = (const float*)d_in[11];
  const float* ad2   = (const float*)d_in[12];
  const float* b2    = (const float*)d_in[13];
  const float* gpw   = (const float*)d_in[14];
  const float* gpb   = (const float*)d_in[15];
  const float* fw    = (const float*)d_in[16];
  const float* fb    = (const float*)d_in[17];
  const float* flng  = (const float*)d_in[18];
  const float* flnb  = (const float*)d_in[19];
  const float* ipw   = (const float*)d_in[20];
  const float* ipb   = (const float*)d_in[21];
  const float* opw   = (const float*)d_in[22];
  const float* opb   = (const float*)d_in[23];
  const float* lng   = (const float*)d_in[24];
  const float* lnb   = (const float*)d_in[25];
  const float* chw   = (const float*)d_in[26];
  const float* chb   = (const float*)d_in[27];
  const float* lfw   = (const float*)d_in[28];
  const float* lsw   = (const float*)d_in[29];
  const float* low   = (const float*)d_in[30];
  const float* lob   = (const float*)d_in[31];
  const float* c2l   = (const float*)d_in[32];
  const float* gsc   = (const float*)d_in[33];
  float* out = (float*)d_out;

  // workspace layout
  int* deg      = (int*)d_ws;
  int* cursor   = deg + NN;
  int* rowstart = cursor + NN;
  int* csr_src  = rowstart + (NN+1);
  int* csr_dst  = csr_src + ET;
  int* incl     = csr_dst + ET;
  int* csum     = incl + NN;
  size_t iw = (size_t)NN*2 + (size_t)(NN+1) + (size_t)ET*2 + (size_t)NN + 64;
  float* fbase = (float*)d_ws + ((iw+3) & ~(size_t)3);
  float* ebuf  = fbase;                        // ET*4
  float* asrcb = ebuf  + (size_t)ET*4;         // NN*4
  float* adstb = asrcb + (size_t)NN*4;         // NN*4
  float* bufA  = adstb + (size_t)NN*4;         // NN*256
  float* bufB  = bufA  + (size_t)NN*256;       // NN*256
  float* gselb = bufB  + (size_t)NN*256;       // NC*256
  float* gatc  = gselb + (size_t)NC*256;       // NC*768
  float* fusedb= gatc  + (size_t)NC*HH;        // NC*1536
  float* kvb   = fusedb+ (size_t)NC*1536;      // NC*1536
  float* enhb  = kvb   + (size_t)NC*1536;      // NC*768
  // bf16 weight split scratch (appended; ~2.6 MB)
  ushort* Wth  = (ushort*)(enhb + (size_t)NC*HH);   // 256*256
  ushort* Wtl  = Wth + 256*256;
  ushort* Wdh  = Wtl + 256*256;                     // 768*768
  ushort* Wdl  = Wdh + 768*768;
  // overlays (lifetimes disjoint with bufA/bufB graph contents)
  float* qb    = bufA;                                  // B*S*H
  float* scb   = bufA + (size_t)BB*SS*HH;               // B*8*S*NC
  float* ctxb  = scb  + (size_t)BB*8*SS*NC;             // B*S*H
  float* ctxt  = bufB;                                  // B*S*H
  float* enrb  = bufB + (size_t)BB*SS*HH;               // B*S*H
  float* Ub    = enrb + (size_t)BB*SS*HH;               // B*S*H
  float* attb  = Ub   + (size_t)BB*SS*HH;               // B*S*NL

  float* out_logits = out;
  float* out_cl = out + 400;
  float* out_cs = out + 1288;
  float* out_lr = out + 2176;
  float* out_aw = out + 309376;
  float* out_gs = out + 764032;

  hipMemsetAsync(deg,    0, sizeof(int)*NN, stream);
  hipMemsetAsync(cursor, 0, sizeof(int)*NN, stream);

  count_deg_k<<<(ET+255)/256,256,0,stream>>>(eidx, deg);
  int nch = (NN+1023)/1024;
  scan1_k<<<nch,1024,0,stream>>>(deg, incl, csum);
  scan2_k<<<1,64,0,stream>>>(csum, nch);
  scan3_k<<<(NN+255)/256,256,0,stream>>>(deg, incl, csum, rowstart);
  fill_csr_k<<<(ET+255)/256,256,0,stream>>>(eidx, rowstart, cursor, csr_src, csr_dst);

  auto gemm = [&](bool tb, const float* A, const float* Bm, const float* bias, float* C,
                  int M, int Nn, int K, int lda, int ldb, int ldc,
                  int nb, int nb2,
                  int64_t sA1,int64_t sA2,int64_t sB1,int64_t sB2,int64_t sC1,int64_t sC2,
                  float alpha, int act){
    dim3 g((Nn+63)/64, (M+127)/128, nb);
    if (tb) gemm_f32<true ><<<g,256,0,stream>>>(A,Bm,bias,C,M,Nn,K,lda,ldb,ldc,nb2,sA1,sA2,sB1,sB2,sC1,sC2,alpha,act);
    else    gemm_f32<false><<<g,256,0,stream>>>(A,Bm,bias,C,M,Nn,K,lda,ldb,ldc,nb2,sA1,sA2,sB1,sB2,sC1,sC2,alpha,act);
  };
  auto skinny = [&](const float* A, const float* Bm, const float* bias, float* C,
                    int M, int Nn, int K, int lda, int ldb, int ldc){
    int ngroups = (Nn+3)>>2;
    int waves = M*ngroups;
    skinny_tb_k<<<(waves+3)/4,256,0,stream>>>(A,Bm,bias,C,M,Nn,K,lda,ldb,ldc);
  };
  auto mfma = [&](const float* A, const ushort* Bh2, const ushort* Bl2, const float* bias,
                  float* C, int M, int Nn, int K, float alpha, int act){
    dim3 g(Nn/64, (M+127)/128);
    gemm_mfma3<<<g,256,0,stream>>>(A, Bh2, Bl2, bias, C, M, Nn, K, alpha, act);
  };

  // ---- GAT layer 1 ----
  split_t_k<<<(256*256+255)/256,256,0,stream>>>(w1, Wth, Wtl, 256, 256);
  mfma(gx, Wth, Wtl, nullptr, bufA, NN, 256, 256, 1.f, 0);
  attcoef1_k<<<(NN+3)/4,256,0,stream>>>(bufA, as1, ad1, asrcb, adstb);
  edge_e1_k<<<(ET+255)/256,256,0,stream>>>(csr_src, csr_dst, asrcb, adstb, ebuf);
  agg1_k<<<(NN+3)/4,256,0,stream>>>(bufA, ebuf, rowstart, csr_src, b1, bufB);
  // ---- GAT layer 2 ----
  split_t_k<<<(256*256+255)/256,256,0,stream>>>(w2, Wth, Wtl, 256, 256);
  mfma(bufB, Wth, Wtl, nullptr, bufA, NN, 256, 256, 1.f, 0);
  attcoef2_k<<<(NN+3)/4,256,0,stream>>>(bufA, as2, ad2, asrcb, adstb);
  edge_e2_k<<<(ET+255)/256,256,0,stream>>>(csr_src, csr_dst, asrcb, adstb, ebuf);
  agg2_k<<<(NN+3)/4,256,0,stream>>>(bufA, ebuf, rowstart, csr_src, b2, bufB);
  // ---- concept path (all small-M: skinny) ----
  gather_gsel_k<<<(NC*256+255)/256,256,0,stream>>>(bufB, cidx, gselb);
  skinny(gselb, gpw, gpb, gatc, NC, HH, 256, 256,256,HH);
  build_fused_k<<<(NC*1536+255)/256,256,0,stream>>>(bert, gatc, fusedb);
  skinny(fusedb, fw, fb, enhb, NC, HH, 1536, 1536,1536,HH);
  ln_k<<<NC,256,0,stream>>>(enhb, nullptr, nullptr, flng, flnb, enhb, 1);
  // K,V for enhanced rows (same for all batches)
  skinny(enhb, ipw + (size_t)768*768, ipb+768, kvb, NC, 1536, 768, 768,768,1536);
  // Q (MFMA, weight = first 768 rows of ipw, already [N][K])
  split_k<<<(768*768+255)/256,256,0,stream>>>(ipw, Wdh, Wdl, 768*768);
  mfma(hs, Wdh, Wdl, ipb, qb, BB*SS, HH, HH, 1.f, 0);
  // scores[b,h]: (512x96)@(111x96)^T / sqrt(96)
  gemm(true, qb, kvb, nullptr, scb, SS, NC, 96, 768, 1536, NC, BB*8, 8,
       (int64_t)SS*HH, 96, 0, 96, (int64_t)8*SS*NC, (int64_t)SS*NC, 0.10206207261596577f, 0);
  softmax_nc_k<<<(BB*8*SS)/4,256,0,stream>>>(scb, BB*8*SS);
  mean_heads_k<<<(int)(((int64_t)BB*SS*NC+255)/256),256,0,stream>>>(scb, out_aw);
  // ctx[b,h]: (512x111)@(111x96)
  gemm(false, scb, kvb+768, nullptr, ctxb, SS, 96, NC, NC, 1536, HH, BB*8, 8,
       (int64_t)8*SS*NC, (int64_t)SS*NC, 0, 96, (int64_t)SS*HH, 96, 1.f, 0);
  // out_proj (MFMA)
  split_k<<<(768*768+255)/256,256,0,stream>>>(opw, Wdh, Wdl, 768*768);
  mfma(ctxb, Wdh, Wdl, opb, ctxt, BB*SS, HH, HH, 1.f, 0);
  // concept logits / scores (M=8: skinny)
  skinny(hs, chw, chb, out_cl, BB, NC, HH, SS*HH, 768, NC);
  sigmoid_k<<<4,256,0,stream>>>(out_cl, out_cs, BB*NC, gsc, out_gs);
  // enriched = LN(hs + sigmoid(gs)*context)
  ln_k<<<BB*SS,256,0,stream>>>(hs, ctxt, gsc, lng, lnb, enrb, 0);
  // LAAT first (MFMA + tanh)
  split_k<<<(768*768+255)/256,256,0,stream>>>(lfw, Wdh, Wdl, 768*768);
  mfma(enrb, Wdh, Wdl, nullptr, Ub, BB*SS, HH, HH, 1.f, 1);
  // att: M=4096, N=50 -> skinny (no bias)
  skinny(Ub, lsw, nullptr, attb, BB*SS, NL, HH, 768,768,NL);
  laat_softmax_k<<<(BB*NL+3)/4,256,0,stream>>>(attb, amask);
  label_reps_k<<<BB*NL,256,0,stream>>>(attb, enrb, out_lr);
  logits_k<<<(BB*NL+3)/4,256,0,stream>>>(out_lr, low, lob, out_cs, c2l, out_logits);
}

// Round 8
// 1129.888 us; speedup vs baseline: 1.7840x; 1.0405x over previous
//
#include <hip/hip_runtime.h>
#include <math.h>
#include <stdint.h>

static constexpr int NN = 50000;      // graph nodes
static constexpr int EE = 800000;     // edges (no self loops)
static constexpr int ET = EE + NN;    // edges + self loops
static constexpr int BB = 8;
static constexpr int SS = 512;
static constexpr int HH = 768;
static constexpr int NC = 111;
static constexpr int NL = 50;

#define DINL __device__ __forceinline__

typedef __attribute__((ext_vector_type(8))) short bf16x8;
typedef __attribute__((ext_vector_type(4))) float f32x4;

DINL float wsum(float v){
  #pragma unroll
  for (int m=1;m<64;m<<=1) v += __shfl_xor(v, m);
  return v;
}
DINL float wmax(float v){
  #pragma unroll
  for (int m=1;m<64;m<<=1) v = fmaxf(v, __shfl_xor(v, m));
  return v;
}
DINL float4 wsum4(float4 v){
  #pragma unroll
  for (int m=1;m<64;m<<=1){
    v.x += __shfl_xor(v.x,m); v.y += __shfl_xor(v.y,m);
    v.z += __shfl_xor(v.z,m); v.w += __shfl_xor(v.w,m);
  }
  return v;
}
DINL float4 wmax4(float4 v){
  #pragma unroll
  for (int m=1;m<64;m<<=1){
    v.x=fmaxf(v.x,__shfl_xor(v.x,m)); v.y=fmaxf(v.y,__shfl_xor(v.y,m));
    v.z=fmaxf(v.z,__shfl_xor(v.z,m)); v.w=fmaxf(v.w,__shfl_xor(v.w,m));
  }
  return v;
}

// ---------------- CSR build ----------------
__global__ void count_deg_k(const int* __restrict__ eidx, int* __restrict__ deg){
  int i = blockIdx.x*256 + threadIdx.x;
  if (i>=ET) return;
  int d = (i<EE)? eidx[EE + i] : (i - EE);
  atomicAdd(&deg[d], 1);
}

__global__ __launch_bounds__(1024) void scan1_k(const int* __restrict__ deg,
                                                int* __restrict__ incl, int* __restrict__ csum){
  __shared__ int sh[1024];
  int tid = threadIdx.x;
  int i = blockIdx.x*1024 + tid;
  int v = (i<NN)? deg[i] : 0;
  sh[tid] = v;
  __syncthreads();
  for (int off=1; off<1024; off<<=1){
    int t = (tid>=off)? sh[tid-off] : 0;
    __syncthreads();
    sh[tid] += t;
    __syncthreads();
  }
  if (i<NN) incl[i] = sh[tid];
  if (tid==1023) csum[blockIdx.x] = sh[1023];
}

__global__ void scan2_k(int* __restrict__ csum, int nch){
  if (threadIdx.x==0 && blockIdx.x==0){
    int run = 0;
    for (int i=0;i<nch;i++){ int v = csum[i]; csum[i] = run; run += v; }
  }
}

__global__ void scan3_k(const int* __restrict__ deg, const int* __restrict__ incl,
                        const int* __restrict__ csum, int* __restrict__ rowstart){
  int i = blockIdx.x*256 + threadIdx.x;
  if (i>=NN) return;
  int ex = csum[i>>10] + incl[i] - deg[i];
  rowstart[i] = ex;
  if (i==NN-1) rowstart[NN] = ex + deg[i];
}

__global__ void fill_csr_k(const int* __restrict__ eidx, const int* __restrict__ rowstart,
                           int* __restrict__ cursor, int* __restrict__ csr_src, int* __restrict__ csr_dst){
  int i = blockIdx.x*256 + threadIdx.x;
  if (i>=ET) return;
  int s, d;
  if (i<EE){ s = eidx[i]; d = eidx[EE+i]; } else { s = i-EE; d = i-EE; }
  int pos = rowstart[d] + atomicAdd(&cursor[d], 1);
  csr_src[pos] = s; csr_dst[pos] = d;
}

// ---------------- bf16 split helpers ----------------
DINL uint bf16_rne(float x){
  uint u = __float_as_uint(x);
  return (u + 0x7FFFu + ((u>>16)&1u)) >> 16;
}
DINL void split8(const float4 v0, const float4 v1, uint4& ph, uint4& pl){
  float xs[8] = {v0.x,v0.y,v0.z,v0.w,v1.x,v1.y,v1.z,v1.w};
  uint hh[8], ll[8];
  #pragma unroll
  for (int i=0;i<8;i++){
    uint hb = bf16_rne(xs[i]);
    float hf = __uint_as_float(hb<<16);
    float lo = xs[i] - hf;
    hh[i] = hb; ll[i] = bf16_rne(lo);
  }
  ph = make_uint4(hh[0]|(hh[1]<<16), hh[2]|(hh[3]<<16), hh[4]|(hh[5]<<16), hh[6]|(hh[7]<<16));
  pl = make_uint4(ll[0]|(ll[1]<<16), ll[2]|(ll[3]<<16), ll[4]|(ll[5]<<16), ll[6]|(ll[7]<<16));
}

// split f32 [n] -> bf16 hi/lo (row-major preserved)
__global__ void split_k(const float* __restrict__ in, ushort* __restrict__ hi,
                        ushort* __restrict__ lo, int n){
  int i = blockIdx.x*256 + threadIdx.x;
  if (i>=n) return;
  float x = in[i];
  uint hb = bf16_rne(x);
  float hf = __uint_as_float(hb<<16);
  hi[i] = (ushort)hb;
  lo[i] = (ushort)bf16_rne(x - hf);
}

// in [R][C] (K x N) -> out [C][R] (N x K), split
__global__ void split_t_k(const float* __restrict__ in, ushort* __restrict__ hi,
                          ushort* __restrict__ lo, int R, int C){
  int i = blockIdx.x*256 + threadIdx.x;
  if (i>=R*C) return;
  int n = i / R, k = i - n*R;
  float x = in[k*C + n];
  uint hb = bf16_rne(x);
  float hf = __uint_as_float(hb<<16);
  hi[i] = (ushort)hb;
  lo[i] = (ushort)bf16_rne(x - hf);
}

// ---------------- bf16x3 MFMA GEMM ----------------
// C[M,N] = act(alpha*(A[M,K] . B[N,K]^T) + bias[n]); A f32 (split in-kernel),
// B pre-split bf16 hi/lo [N][K]. Tile 128x64, BK=64, 256 thr (4 waves, 2Mx2N).
// Optional Cb: bf16 copy of the f32 output (for downstream BW-bound consumers).
// Requires N%64==0, K%64==0.
__global__ __launch_bounds__(256) void gemm_mfma3(
    const float* __restrict__ A, const ushort* __restrict__ Bh, const ushort* __restrict__ Bl,
    const float* __restrict__ bias, float* __restrict__ C, ushort* __restrict__ Cb,
    int M, int N, int K, float alpha, int act)
{
  __shared__ __align__(16) ushort As[2][128*64];
  __shared__ __align__(16) ushort Bs[2][64*64];
  const int tid = threadIdx.x;
  const int lane = tid & 63, wid = tid >> 6;
  const int wm = wid >> 1, wn = wid & 1;
  const int m0 = blockIdx.y*128, n0 = blockIdx.x*64;
  f32x4 acc[4][2];
  #pragma unroll
  for (int i=0;i<4;i++)
    #pragma unroll
    for (int j=0;j<2;j++) acc[i][j] = (f32x4){0.f,0.f,0.f,0.f};

  const int nkt = K >> 6;
  for (int kt=0; kt<nkt; ++kt){
    // stage A (f32 -> hi/lo planes)
    #pragma unroll
    for (int q=0;q<4;q++){
      int idx = q*256 + tid;       // 0..1023
      int row = idx >> 3;          // 0..127
      int g8  = idx & 7;           // group of 8 floats
      int rowg = m0 + row; if (rowg >= M) rowg = M-1;
      const float* src = A + (int64_t)rowg*K + (kt<<6) + g8*8;
      float4 v0 = ((const float4*)src)[0];
      float4 v1 = ((const float4*)src)[1];
      uint4 ph, pl;
      split8(v0, v1, ph, pl);
      int off = row*64 + ((g8*8) ^ ((row&7)<<3));
      *(uint4*)&As[0][off] = ph;
      *(uint4*)&As[1][off] = pl;
    }
    // stage B (already bf16 hi/lo)
    #pragma unroll
    for (int q=0;q<4;q++){
      int idx = q*256 + tid;       // 0..1023
      int plane = idx >> 9;
      int rem = idx & 511;
      int row = rem >> 3;          // 0..63
      int g8 = rem & 7;
      const ushort* src = (plane ? Bl : Bh) + (int64_t)(n0+row)*K + (kt<<6) + g8*8;
      uint4 v = *(const uint4*)src;
      int off = row*64 + ((g8*8) ^ ((row&7)<<3));
      *(uint4*)&Bs[plane][off] = v;
    }
    __syncthreads();
    #pragma unroll
    for (int ks=0; ks<2; ks++){
      const int kswz = ks*32 + ((lane>>4)<<3);
      bf16x8 ah[4], al[4], bh[2], bl[2];
      #pragma unroll
      for (int mi=0;mi<4;mi++){
        int r = wm*64 + mi*16 + (lane&15);
        int off = r*64 + (kswz ^ ((r&7)<<3));
        ah[mi] = *(const bf16x8*)&As[0][off];
        al[mi] = *(const bf16x8*)&As[1][off];
      }
      #pragma unroll
      for (int nj=0;nj<2;nj++){
        int r = wn*32 + nj*16 + (lane&15);
        int off = r*64 + (kswz ^ ((r&7)<<3));
        bh[nj] = *(const bf16x8*)&Bs[0][off];
        bl[nj] = *(const bf16x8*)&Bs[1][off];
      }
      #pragma unroll
      for (int mi=0;mi<4;mi++)
        #pragma unroll
        for (int nj=0;nj<2;nj++){
          acc[mi][nj] = __builtin_amdgcn_mfma_f32_16x16x32_bf16(ah[mi], bh[nj], acc[mi][nj], 0,0,0);
          acc[mi][nj] = __builtin_amdgcn_mfma_f32_16x16x32_bf16(ah[mi], bl[nj], acc[mi][nj], 0,0,0);
          acc[mi][nj] = __builtin_amdgcn_mfma_f32_16x16x32_bf16(al[mi], bh[nj], acc[mi][nj], 0,0,0);
        }
    }
    __syncthreads();
  }
  // epilogue: C row = (lane>>4)*4 + j, col = lane&15
  const int crow = (lane>>4)*4, ccol = lane&15;
  #pragma unroll
  for (int nj=0;nj<2;nj++){
    int n = n0 + wn*32 + nj*16 + ccol;
    float bv = bias ? bias[n] : 0.f;
    #pragma unroll
    for (int mi=0;mi<4;mi++){
      #pragma unroll
      for (int j=0;j<4;j++){
        int m = m0 + wm*64 + mi*16 + crow + j;
        if (m < M){
          float v = acc[mi][nj][j]*alpha + bv;
          if (act==1) v = tanhf(v);
          C[(int64_t)m*N + n] = v;
          if (Cb) Cb[(int64_t)m*N + n] = (ushort)bf16_rne(v);
        }
      }
    }
  }
}

// ---------------- generic f32 GEMM (128x64 tile, 8x4 per-thread) ----------------
template<bool TB>
__global__ __launch_bounds__(256) void gemm_f32(
    const float* __restrict__ A, const float* __restrict__ Bm,
    const float* __restrict__ bias, float* __restrict__ C,
    int M, int N, int K, int lda, int ldb, int ldc,
    int nb2,
    int64_t sA1, int64_t sA2, int64_t sB1, int64_t sB2, int64_t sC1, int64_t sC2,
    float alpha, int act)
{
  int z = blockIdx.z;
  int z1 = z / nb2, z2 = z - z1*nb2;
  A  += z1*sA1 + z2*sA2;
  Bm += z1*sB1 + z2*sB2;
  C  += z1*sC1 + z2*sC2;
  __shared__ __align__(16) float sA[16][132];
  __shared__ __align__(16) float sB[16][68];
  const int tid = threadIdx.x;
  const int m0 = blockIdx.y*128, n0 = blockIdx.x*64;
  const int tx = tid & 15, ty = tid >> 4;
  float acc[8][4] = {};
  for (int k0=0; k0<K; k0+=16){
    {
      int kk = tid & 15, mm = tid >> 4;
      #pragma unroll
      for (int r=0;r<8;r++){
        int m = m0 + mm + r*16, k = k0 + kk;
        float v = 0.f;
        if (m<M && k<K) v = A[(int64_t)m*lda + k];
        sA[kk][mm + r*16] = v;
      }
    }
    if (!TB){
      int nn = tid & 63, kb = tid >> 6;
      #pragma unroll
      for (int r=0;r<4;r++){
        int k = k0 + kb + r*4, n = n0 + nn;
        float v=0.f;
        if (k<K && n<N) v = Bm[(int64_t)k*ldb + n];
        sB[kb + r*4][nn] = v;
      }
    } else {
      int kk = tid & 15, nn = tid >> 4;
      #pragma unroll
      for (int r=0;r<4;r++){
        int n = n0 + nn + r*16, k = k0 + kk;
        float v=0.f;
        if (n<N && k<K) v = Bm[(int64_t)n*ldb + k];
        sB[kk][nn + r*16] = v;
      }
    }
    __syncthreads();
    #pragma unroll
    for (int k=0;k<16;k++){
      float4 a0 = *(const float4*)&sA[k][ty*8];
      float4 a1 = *(const float4*)&sA[k][ty*8+4];
      float4 b  = *(const float4*)&sB[k][tx*4];
      float av[8] = {a0.x,a0.y,a0.z,a0.w,a1.x,a1.y,a1.z,a1.w};
      float bv[4] = {b.x,b.y,b.z,b.w};
      #pragma unroll
      for (int i=0;i<8;i++)
        #pragma unroll
        for (int j=0;j<4;j++)
          acc[i][j] += av[i]*bv[j];
    }
    __syncthreads();
  }
  #pragma unroll
  for (int i=0;i<8;i++){
    int m = m0 + ty*8 + i;
    if (m>=M) continue;
    #pragma unroll
    for (int j=0;j<4;j++){
      int n = n0 + tx*4 + j;
      if (n>=N) continue;
      float v = acc[i][j]*alpha;
      if (bias) v += bias[n];
      if (act==1) v = tanhf(v);
      C[(int64_t)m*ldc + n] = v;
    }
  }
}

// ---------------- skinny GEMM: C[M,N] = A[M,K] @ B[N,K]^T + bias ----------------
__global__ __launch_bounds__(256) void skinny_tb_k(
    const float* __restrict__ A, const float* __restrict__ B,
    const float* __restrict__ bias, float* __restrict__ C,
    int M, int N, int K, int lda, int ldb, int ldc)
{
  int ngroups = (N+3)>>2;
  int w = blockIdx.x*4 + (threadIdx.x>>6);
  if (w >= M*ngroups) return;
  int lane = threadIdx.x & 63;
  int m = w / ngroups, ng = w - m*ngroups;
  int n0 = ng*4;
  const float4* a4 = (const float4*)(A + (int64_t)m*lda);
  int r0 = n0, r1 = (n0+1<N)? n0+1 : N-1, r2 = (n0+2<N)? n0+2 : N-1, r3 = (n0+3<N)? n0+3 : N-1;
  const float4* b0 = (const float4*)(B + (int64_t)r0*ldb);
  const float4* b1 = (const float4*)(B + (int64_t)r1*ldb);
  const float4* b2 = (const float4*)(B + (int64_t)r2*ldb);
  const float4* b3 = (const float4*)(B + (int64_t)r3*ldb);
  float4 acc = make_float4(0.f,0.f,0.f,0.f);
  int K4 = K>>2;
  for (int i=lane; i<K4; i+=64){
    float4 av = a4[i];
    float4 v0 = b0[i], v1 = b1[i], v2 = b2[i], v3 = b3[i];
    acc.x += av.x*v0.x + av.y*v0.y + av.z*v0.z + av.w*v0.w;
    acc.y += av.x*v1.x + av.y*v1.y + av.z*v1.z + av.w*v1.w;
    acc.z += av.x*v2.x + av.y*v2.y + av.z*v2.z + av.w*v2.w;
    acc.w += av.x*v3.x + av.y*v3.y + av.z*v3.z + av.w*v3.w;
  }
  acc = wsum4(acc);
  if (lane==0){
    float vals[4] = {acc.x, acc.y, acc.z, acc.w};
    #pragma unroll
    for (int j=0;j<4;j++){
      int n = n0+j;
      if (n<N){
        float v = vals[j];
        if (bias) v += bias[n];
        C[(int64_t)m*ldc + n] = v;
      }
    }
  }
}

// ---------------- GAT helpers ----------------
__global__ __launch_bounds__(256) void attcoef1_k(const float* __restrict__ h,
    const float* __restrict__ a_src, const float* __restrict__ a_dst,
    float* __restrict__ asrc, float* __restrict__ adst){
  int node = blockIdx.x*4 + (threadIdx.x>>6);
  if (node>=NN) return;
  int lane = threadIdx.x & 63;
  float4 hv = ((const float4*)h)[(int64_t)node*64 + lane];
  int head = lane >> 4;
  float4 as = ((const float4*)a_src)[head*16 + (lane&15)];
  float4 ad = ((const float4*)a_dst)[head*16 + (lane&15)];
  float ps = hv.x*as.x + hv.y*as.y + hv.z*as.z + hv.w*as.w;
  float pd = hv.x*ad.x + hv.y*ad.y + hv.z*ad.z + hv.w*ad.w;
  #pragma unroll
  for (int m=1;m<16;m<<=1){ ps += __shfl_xor(ps,m); pd += __shfl_xor(pd,m); }
  if ((lane&15)==0){ asrc[node*4+head]=ps; adst[node*4+head]=pd; }
}

__global__ __launch_bounds__(256) void attcoef2_k(const float* __restrict__ h,
    const float* __restrict__ a_src, const float* __restrict__ a_dst,
    float* __restrict__ asrc, float* __restrict__ adst){
  int node = blockIdx.x*4 + (threadIdx.x>>6);
  if (node>=NN) return;
  int lane = threadIdx.x & 63;
  float4 hv = ((const float4*)h)[(int64_t)node*64 + lane];
  float4 as = ((const float4*)a_src)[lane];
  float4 ad = ((const float4*)a_dst)[lane];
  float ps = hv.x*as.x + hv.y*as.y + hv.z*as.z + hv.w*as.w;
  float pd = hv.x*ad.x + hv.y*ad.y + hv.z*ad.z + hv.w*ad.w;
  ps = wsum(ps); pd = wsum(pd);
  if (lane==0){ asrc[node]=ps; adst[node]=pd; }
}

__global__ void edge_e1_k(const int* __restrict__ csr_src, const int* __restrict__ csr_dst,
                          const float* __restrict__ asrc, const float* __restrict__ adst,
                          float* __restrict__ ebuf){
  int p = blockIdx.x*256 + threadIdx.x;
  if (p>=ET) return;
  int s = csr_src[p], d = csr_dst[p];
  float4 a = ((const float4*)asrc)[s];
  float4 b = ((const float4*)adst)[d];
  float4 e;
  e.x = a.x+b.x; e.x = (e.x>=0.f)? e.x : 0.2f*e.x;
  e.y = a.y+b.y; e.y = (e.y>=0.f)? e.y : 0.2f*e.y;
  e.z = a.z+b.z; e.z = (e.z>=0.f)? e.z : 0.2f*e.z;
  e.w = a.w+b.w; e.w = (e.w>=0.f)? e.w : 0.2f*e.w;
  ((float4*)ebuf)[p] = e;
}

__global__ void edge_e2_k(const int* __restrict__ csr_src, const int* __restrict__ csr_dst,
                          const float* __restrict__ asrc, const float* __restrict__ adst,
                          float* __restrict__ ebuf){
  int p = blockIdx.x*256 + threadIdx.x;
  if (p>=ET) return;
  int s = csr_src[p], d = csr_dst[p];
  float e = asrc[s] + adst[d];
  e = (e>=0.f)? e : 0.2f*e;
  ebuf[p] = e;
}

// layer1 agg: h in bf16 (hb), 4 heads of 64ch; lane covers ch 4*lane..4*lane+3.
__global__ __launch_bounds__(256) void agg1_k(const ushort* __restrict__ hb, const float* __restrict__ ebuf,
    const int* __restrict__ rowstart, const int* __restrict__ csr_src,
    const float* __restrict__ bias, float* __restrict__ outp){
  int node = blockIdx.x*4 + (threadIdx.x>>6);
  if (node>=NN) return;
  int lane = threadIdx.x & 63;
  int rs = rowstart[node], re = rowstart[node+1];
  const float4* e4 = (const float4*)ebuf;
  float4 mx = make_float4(-INFINITY,-INFINITY,-INFINITY,-INFINITY);
  for (int p=rs+lane; p<re; p+=64){
    float4 e = e4[p];
    mx.x=fmaxf(mx.x,e.x); mx.y=fmaxf(mx.y,e.y); mx.z=fmaxf(mx.z,e.z); mx.w=fmaxf(mx.w,e.w);
  }
  mx = wmax4(mx);
  float4 sm = make_float4(0.f,0.f,0.f,0.f);
  for (int p=rs+lane; p<re; p+=64){
    float4 e = e4[p];
    sm.x += expf(e.x-mx.x); sm.y += expf(e.y-mx.y);
    sm.z += expf(e.z-mx.z); sm.w += expf(e.w-mx.w);
  }
  sm = wsum4(sm);
  int head = lane>>4;
  float m_h = head==0?mx.x:head==1?mx.y:head==2?mx.z:mx.w;
  float s_h = head==0?sm.x:head==1?sm.y:head==2?sm.z:sm.w;
  float dinv = 1.f/(s_h+1e-16f);
  const ushort4* h4 = (const ushort4*)hb;
  float4 acc = make_float4(0.f,0.f,0.f,0.f);
  for (int p=rs; p<re; ++p){
    int s = csr_src[p];
    float w = expf(ebuf[p*4+head]-m_h)*dinv;
    ushort4 hu = h4[(int64_t)s*64 + lane];
    acc.x += w*__uint_as_float(((uint)hu.x)<<16);
    acc.y += w*__uint_as_float(((uint)hu.y)<<16);
    acc.z += w*__uint_as_float(((uint)hu.z)<<16);
    acc.w += w*__uint_as_float(((uint)hu.w)<<16);
  }
  float4 bb = ((const float4*)bias)[lane];
  float4 o;
  o.x = acc.x+bb.x; o.x = (o.x>0.f)? o.x : expm1f(o.x);
  o.y = acc.y+bb.y; o.y = (o.y>0.f)? o.y : expm1f(o.y);
  o.z = acc.z+bb.z; o.z = (o.z>0.f)? o.z : expm1f(o.z);
  o.w = acc.w+bb.w; o.w = (o.w>0.f)? o.w : expm1f(o.w);
  ((float4*)outp)[(int64_t)node*64 + lane] = o;
}

// layer2 agg: h in bf16, single head over 256 ch. +bias, no act.
__global__ __launch_bounds__(256) void agg2_k(const ushort* __restrict__ hb, const float* __restrict__ ebuf,
    const int* __restrict__ rowstart, const int* __restrict__ csr_src,
    const float* __restrict__ bias, float* __restrict__ outp){
  int node = blockIdx.x*4 + (threadIdx.x>>6);
  if (node>=NN) return;
  int lane = threadIdx.x & 63;
  int rs = rowstart[node], re = rowstart[node+1];
  float mx = -INFINITY;
  for (int p=rs+lane; p<re; p+=64) mx = fmaxf(mx, ebuf[p]);
  mx = wmax(mx);
  float sm = 0.f;
  for (int p=rs+lane; p<re; p+=64) sm += expf(ebuf[p]-mx);
  sm = wsum(sm);
  float dinv = 1.f/(sm+1e-16f);
  const ushort4* h4 = (const ushort4*)hb;
  float4 acc = make_float4(0.f,0.f,0.f,0.f);
  for (int p=rs; p<re; ++p){
    int s = csr_src[p];
    float w = expf(ebuf[p]-mx)*dinv;
    ushort4 hu = h4[(int64_t)s*64 + lane];
    acc.x += w*__uint_as_float(((uint)hu.x)<<16);
    acc.y += w*__uint_as_float(((uint)hu.y)<<16);
    acc.z += w*__uint_as_float(((uint)hu.z)<<16);
    acc.w += w*__uint_as_float(((uint)hu.w)<<16);
  }
  float4 bb = ((const float4*)bias)[lane];
  float4 o = make_float4(acc.x+bb.x, acc.y+bb.y, acc.z+bb.z, acc.w+bb.w);
  ((float4*)outp)[(int64_t)node*64 + lane] = o;
}

// ---------------- small glue kernels ----------------
__global__ void gather_gsel_k(const float* __restrict__ out2, const int* __restrict__ cidx,
                              float* __restrict__ gsel){
  int idx = blockIdx.x*256 + threadIdx.x;
  if (idx >= NC*256) return;
  int i = idx >> 8, c = idx & 255;
  gsel[idx] = out2[(int64_t)cidx[i]*256 + c];
}

__global__ void build_fused_k(const float* __restrict__ bert, const float* __restrict__ gatc,
                              float* __restrict__ fused){
  int idx = blockIdx.x*256 + threadIdx.x;
  if (idx >= NC*1536) return;
  int i = idx / 1536, c = idx - i*1536;
  fused[idx] = (c<768)? bert[(int64_t)i*768 + c] : gatc[(int64_t)i*768 + (c-768)];
}

__global__ __launch_bounds__(256) void ln_k(const float* __restrict__ x1, const float* __restrict__ x2,
    const float* __restrict__ gsptr, const float* __restrict__ g, const float* __restrict__ bb,
    float* __restrict__ outp, int relu){
  __shared__ float red[4];
  int row = blockIdx.x;
  int t = threadIdx.x;
  float gs = 0.f;
  if (x2) gs = 1.f/(1.f+expf(-gsptr[0]));
  const float* xr = x1 + (int64_t)row*768;
  float v0 = xr[t], v1 = xr[t+256], v2 = xr[t+512];
  if (x2){
    const float* x2r = x2 + (int64_t)row*768;
    v0 += gs*x2r[t]; v1 += gs*x2r[t+256]; v2 += gs*x2r[t+512];
  }
  int lane = t&63, wid = t>>6;
  float s = wsum(v0+v1+v2);
  if (lane==0) red[wid]=s;
  __syncthreads();
  float mean = (red[0]+red[1]+red[2]+red[3]) * (1.f/768.f);
  __syncthreads();
  float d0=v0-mean, d1=v1-mean, d2=v2-mean;
  float ss = wsum(d0*d0+d1*d1+d2*d2);
  if (lane==0) red[wid]=ss;
  __syncthreads();
  float var = (red[0]+red[1]+red[2]+red[3]) * (1.f/768.f);
  float rstd = rsqrtf(var + 1e-5f);
  float o0 = d0*rstd*g[t]+bb[t];
  float o1 = d1*rstd*g[t+256]+bb[t+256];
  float o2 = d2*rstd*g[t+512]+bb[t+512];
  if (relu){ o0=fmaxf(o0,0.f); o1=fmaxf(o1,0.f); o2=fmaxf(o2,0.f); }
  float* orow = outp + (int64_t)row*768;
  orow[t]=o0; orow[t+256]=o1; orow[t+512]=o2;
}

__global__ __launch_bounds__(256) void softmax_nc_k(float* __restrict__ sc, int rows){
  int row = blockIdx.x*4 + (threadIdx.x>>6);
  if (row>=rows) return;
  int lane = threadIdx.x & 63;
  float* r = sc + (int64_t)row*NC;
  float x0 = r[lane];
  float x1 = (lane+64<NC)? r[lane+64] : -INFINITY;
  float m = wmax(fmaxf(x0,x1));
  float p0 = expf(x0-m);
  float p1 = (lane+64<NC)? expf(x1-m) : 0.f;
  float s = wsum(p0+p1);
  float dinv = 1.f/s;
  r[lane] = p0*dinv;
  if (lane+64<NC) r[lane+64] = p1*dinv;
}

__global__ void mean_heads_k(const float* __restrict__ attn, float* __restrict__ outp){
  int64_t idx = (int64_t)blockIdx.x*256 + threadIdx.x;
  if (idx >= (int64_t)BB*SS*NC) return;
  int c = idx % NC;
  int64_t r = idx / NC;
  int s = r % SS;
  int b = r / SS;
  float acc = 0.f;
  #pragma unroll
  for (int h=0;h<8;h++)
    acc += attn[(((int64_t)(b*8+h)*SS)+s)*NC + c];
  outp[idx] = acc * 0.125f;
}

__global__ void sigmoid_k(const float* __restrict__ in, float* __restrict__ outp, int n,
                          const float* __restrict__ gsptr, float* __restrict__ gsout){
  int idx = blockIdx.x*256 + threadIdx.x;
  if (idx < n) outp[idx] = 1.f/(1.f+expf(-in[idx]));
  if (idx == 0) gsout[0] = 1.f/(1.f+expf(-gsptr[0]));
}

__global__ __launch_bounds__(256) void laat_softmax_k(float* __restrict__ att, const int* __restrict__ mask){
  int idx = blockIdx.x*4 + (threadIdx.x>>6);
  if (idx >= BB*NL) return;
  int lane = threadIdx.x & 63;
  int b = idx / NL, l = idx - b*NL;
  float x[8];
  #pragma unroll
  for (int i=0;i<8;i++){
    int s = lane + i*64;
    int mk = mask[b*SS + s];
    x[i] = mk ? att[((int64_t)(b*SS+s))*NL + l] : -INFINITY;
  }
  float m = -INFINITY;
  #pragma unroll
  for (int i=0;i<8;i++) m = fmaxf(m, x[i]);
  m = wmax(m);
  float p[8]; float sm = 0.f;
  #pragma unroll
  for (int i=0;i<8;i++){ p[i] = expf(x[i]-m); sm += p[i]; }
  sm = wsum(sm);
  float dinv = 1.f/sm;
  #pragma unroll
  for (int i=0;i<8;i++){
    int s = lane + i*64;
    att[((int64_t)(b*SS+s))*NL + l] = p[i]*dinv;
  }
}

__global__ __launch_bounds__(256) void label_reps_k(const float* __restrict__ w,
    const float* __restrict__ enr, float* __restrict__ outp){
  __shared__ __align__(16) float part[4][768];
  int bl = blockIdx.x;
  int b = bl / NL, l = bl - b*NL;
  int t = threadIdx.x;
  int wid = t>>6, lane = t&63;
  const float* wb = w + (int64_t)b*SS*NL + l;
  const float* eb = enr + (int64_t)b*SS*768;
  float4 a0 = make_float4(0,0,0,0), a1 = a0, a2 = a0;
  for (int s=wid; s<SS; s+=4){
    float wv = wb[(int64_t)s*NL];
    const float4* row = (const float4*)(eb + (int64_t)s*768);
    float4 r0 = row[lane], r1 = row[lane+64], r2 = row[lane+128];
    a0.x += wv*r0.x; a0.y += wv*r0.y; a0.z += wv*r0.z; a0.w += wv*r0.w;
    a1.x += wv*r1.x; a1.y += wv*r1.y; a1.z += wv*r1.z; a1.w += wv*r1.w;
    a2.x += wv*r2.x; a2.y += wv*r2.y; a2.z += wv*r2.z; a2.w += wv*r2.w;
  }
  ((float4*)&part[wid][lane*4      ])[0] = a0;
  ((float4*)&part[wid][lane*4 + 256])[0] = a1;
  ((float4*)&part[wid][lane*4 + 512])[0] = a2;
  __syncthreads();
  float* o = outp + (int64_t)bl*768;
  #pragma unroll
  for (int q=0;q<3;q++){
    int ch = t + q*256;
    o[ch] = part[0][ch] + part[1][ch] + part[2][ch] + part[3][ch];
  }
}

__global__ __launch_bounds__(256) void logits_k(const float* __restrict__ lr,
    const float* __restrict__ low, const float* __restrict__ lob,
    const float* __restrict__ cs, const float* __restrict__ c2l,
    float* __restrict__ logits){
  int idx = blockIdx.x*4 + (threadIdx.x>>6);
  if (idx >= BB*NL) return;
  int lane = threadIdx.x & 63;
  int b = idx / NL, l = idx - b*NL;
  const float* r = lr + (int64_t)idx*768;
  float acc = 0.f;
  for (int c=lane;c<768;c+=64) acc += r[c]*low[c];
  for (int c=lane;c<NC;c+=64)  acc += cs[b*NC+c]*c2l[l*NC+c];
  acc = wsum(acc);
  if (lane==0) logits[idx] = acc + lob[0];
}

// ---------------- host ----------------
extern "C" void kernel_launch(void* const* d_in, const int* in_sizes, int n_in,
                              void* d_out, int out_size, void* d_ws, size_t ws_size,
                              hipStream_t stream)
{
  const float* hs    = (const float*)d_in[0];
  const int*   amask = (const int*)d_in[1];
  const float* bert  = (const float*)d_in[2];
  const float* gx    = (const float*)d_in[3];
  const int*   eidx  = (const int*)d_in[4];
  const int*   cidx  = (const int*)d_in[5];
  const float* w1    = (const float*)d_in[6];
  const float* as1   = (const float*)d_in[7];
  const float* ad1   = (const float*)d_in[8];
  const float* b1    = (const float*)d_in[9];
  const float* w2    = (const float*)d_in[10];
  const float* as2   = (const float*)d_in[11];
  const float* ad2   = (const float*)d_in[12];
  const float* b2    = (const float*)d_in[13];
  const float* gpw   = (const float*)d_in[14];
  const float* gpb   = (const float*)d_in[15];
  const float* fw    = (const float*)d_in[16];
  const float* fb    = (const float*)d_in[17];
  const float* flng  = (const float*)d_in[18];
  const float* flnb  = (const float*)d_in[19];
  const float* ipw   = (const float*)d_in[20];
  const float* ipb   = (const float*)d_in[21];
  const float* opw   = (const float*)d_in[22];
  const float* opb   = (const float*)d_in[23];
  const float* lng   = (const float*)d_in[24];
  const float* lnb   = (const float*)d_in[25];
  const float* chw   = (const float*)d_in[26];
  const float* chb   = (const float*)d_in[27];
  const float* lfw   = (const float*)d_in[28];
  const float* lsw   = (const float*)d_in[29];
  const float* low   = (const float*)d_in[30];
  const float* lob   = (const float*)d_in[31];
  const float* c2l   = (const float*)d_in[32];
  const float* gsc   = (const float*)d_in[33];
  float* out = (float*)d_out;

  // workspace layout
  int* deg      = (int*)d_ws;
  int* cursor   = deg + NN;
  int* rowstart = cursor + NN;
  int* csr_src  = rowstart + (NN+1);
  int* csr_dst  = csr_src + ET;
  int* incl     = csr_dst + ET;
  int* csum     = incl + NN;
  size_t iw = (size_t)NN*2 + (size_t)(NN+1) + (size_t)ET*2 + (size_t)NN + 64;
  float* fbase = (float*)d_ws + ((iw+3) & ~(size_t)3);
  float* ebuf  = fbase;                        // ET*4
  float* asrcb = ebuf  + (size_t)ET*4;         // NN*4
  float* adstb = asrcb + (size_t)NN*4;         // NN*4
  float* bufA  = adstb + (size_t)NN*4;         // NN*256
  float* bufB  = bufA  + (size_t)NN*256;       // NN*256
  float* gselb = bufB  + (size_t)NN*256;       // NC*256
  float* gatc  = gselb + (size_t)NC*256;       // NC*768
  float* fusedb= gatc  + (size_t)NC*HH;        // NC*1536
  float* kvb   = fusedb+ (size_t)NC*1536;      // NC*1536
  float* enhb  = kvb   + (size_t)NC*1536;      // NC*768
  // bf16 weight split scratch + bf16 h copy
  ushort* Wth  = (ushort*)(enhb + (size_t)NC*HH);   // 256*256
  ushort* Wtl  = Wth + 256*256;
  ushort* Wdh  = Wtl + 256*256;                     // 768*768
  ushort* Wdl  = Wdh + 768*768;
  ushort* hbb  = Wdl + 768*768;                     // NN*256 bf16 (25.6 MB)
  // overlays (lifetimes disjoint with bufA/bufB graph contents)
  float* qb    = bufA;                                  // B*S*H
  float* scb   = bufA + (size_t)BB*SS*HH;               // B*8*S*NC
  float* ctxb  = scb  + (size_t)BB*8*SS*NC;             // B*S*H
  float* ctxt  = bufB;                                  // B*S*H
  float* enrb  = bufB + (size_t)BB*SS*HH;               // B*S*H
  float* Ub    = enrb + (size_t)BB*SS*HH;               // B*S*H
  float* attb  = Ub   + (size_t)BB*SS*HH;               // B*S*NL

  float* out_logits = out;
  float* out_cl = out + 400;
  float* out_cs = out + 1288;
  float* out_lr = out + 2176;
  float* out_aw = out + 309376;
  float* out_gs = out + 764032;

  hipMemsetAsync(deg,    0, sizeof(int)*NN, stream);
  hipMemsetAsync(cursor, 0, sizeof(int)*NN, stream);

  count_deg_k<<<(ET+255)/256,256,0,stream>>>(eidx, deg);
  int nch = (NN+1023)/1024;
  scan1_k<<<nch,1024,0,stream>>>(deg, incl, csum);
  scan2_k<<<1,64,0,stream>>>(csum, nch);
  scan3_k<<<(NN+255)/256,256,0,stream>>>(deg, incl, csum, rowstart);
  fill_csr_k<<<(ET+255)/256,256,0,stream>>>(eidx, rowstart, cursor, csr_src, csr_dst);

  auto gemm = [&](bool tb, const float* A, const float* Bm, const float* bias, float* C,
                  int M, int Nn, int K, int lda, int ldb, int ldc,
                  int nb, int nb2,
                  int64_t sA1,int64_t sA2,int64_t sB1,int64_t sB2,int64_t sC1,int64_t sC2,
                  float alpha, int act){
    dim3 g((Nn+63)/64, (M+127)/128, nb);
    if (tb) gemm_f32<true ><<<g,256,0,stream>>>(A,Bm,bias,C,M,Nn,K,lda,ldb,ldc,nb2,sA1,sA2,sB1,sB2,sC1,sC2,alpha,act);
    else    gemm_f32<false><<<g,256,0,stream>>>(A,Bm,bias,C,M,Nn,K,lda,ldb,ldc,nb2,sA1,sA2,sB1,sB2,sC1,sC2,alpha,act);
  };
  auto skinny = [&](const float* A, const float* Bm, const float* bias, float* C,
                    int M, int Nn, int K, int lda, int ldb, int ldc){
    int ngroups = (Nn+3)>>2;
    int waves = M*ngroups;
    skinny_tb_k<<<(waves+3)/4,256,0,stream>>>(A,Bm,bias,C,M,Nn,K,lda,ldb,ldc);
  };
  auto mfma = [&](const float* A, const ushort* Bh2, const ushort* Bl2, const float* bias,
                  float* C, ushort* Cb, int M, int Nn, int K, float alpha, int act){
    dim3 g(Nn/64, (M+127)/128);
    gemm_mfma3<<<g,256,0,stream>>>(A, Bh2, Bl2, bias, C, Cb, M, Nn, K, alpha, act);
  };

  // ---- GAT layer 1 ----
  split_t_k<<<(256*256+255)/256,256,0,stream>>>(w1, Wth, Wtl, 256, 256);
  mfma(gx, Wth, Wtl, nullptr, bufA, hbb, NN, 256, 256, 1.f, 0);
  attcoef1_k<<<(NN+3)/4,256,0,stream>>>(bufA, as1, ad1, asrcb, adstb);
  edge_e1_k<<<(ET+255)/256,256,0,stream>>>(csr_src, csr_dst, asrcb, adstb, ebuf);
  agg1_k<<<(NN+3)/4,256,0,stream>>>(hbb, ebuf, rowstart, csr_src, b1, bufB);
  // ---- GAT layer 2 ----
  split_t_k<<<(256*256+255)/256,256,0,stream>>>(w2, Wth, Wtl, 256, 256);
  mfma(bufB, Wth, Wtl, nullptr, bufA, hbb, NN, 256, 256, 1.f, 0);
  attcoef2_k<<<(NN+3)/4,256,0,stream>>>(bufA, as2, ad2, asrcb, adstb);
  edge_e2_k<<<(ET+255)/256,256,0,stream>>>(csr_src, csr_dst, asrcb, adstb, ebuf);
  agg2_k<<<(NN+3)/4,256,0,stream>>>(hbb, ebuf, rowstart, csr_src, b2, bufB);
  // ---- concept path (all small-M: skinny) ----
  gather_gsel_k<<<(NC*256+255)/256,256,0,stream>>>(bufB, cidx, gselb);
  skinny(gselb, gpw, gpb, gatc, NC, HH, 256, 256,256,HH);
  build_fused_k<<<(NC*1536+255)/256,256,0,stream>>>(bert, gatc, fusedb);
  skinny(fusedb, fw, fb, enhb, NC, HH, 1536, 1536,1536,HH);
  ln_k<<<NC,256,0,stream>>>(enhb, nullptr, nullptr, flng, flnb, enhb, 1);
  // K,V for enhanced rows (same for all batches)
  skinny(enhb, ipw + (size_t)768*768, ipb+768, kvb, NC, 1536, 768, 768,768,1536);
  // Q (MFMA, weight = first 768 rows of ipw, already [N][K])
  split_k<<<(768*768+255)/256,256,0,stream>>>(ipw, Wdh, Wdl, 768*768);
  mfma(hs, Wdh, Wdl, ipb, qb, nullptr, BB*SS, HH, HH, 1.f, 0);
  // scores[b,h]: (512x96)@(111x96)^T / sqrt(96)
  gemm(true, qb, kvb, nullptr, scb, SS, NC, 96, 768, 1536, NC, BB*8, 8,
       (int64_t)SS*HH, 96, 0, 96, (int64_t)8*SS*NC, (int64_t)SS*NC, 0.10206207261596577f, 0);
  softmax_nc_k<<<(BB*8*SS)/4,256,0,stream>>>(scb, BB*8*SS);
  mean_heads_k<<<(int)(((int64_t)BB*SS*NC+255)/256),256,0,stream>>>(scb, out_aw);
  // ctx[b,h]: (512x111)@(111x96)
  gemm(false, scb, kvb+768, nullptr, ctxb, SS, 96, NC, NC, 1536, HH, BB*8, 8,
       (int64_t)8*SS*NC, (int64_t)SS*NC, 0, 96, (int64_t)SS*HH, 96, 1.f, 0);
  // out_proj (MFMA)
  split_k<<<(768*768+255)/256,256,0,stream>>>(opw, Wdh, Wdl, 768*768);
  mfma(ctxb, Wdh, Wdl, opb, ctxt, nullptr, BB*SS, HH, HH, 1.f, 0);
  // concept logits / scores (M=8: skinny)
  skinny(hs, chw, chb, out_cl, BB, NC, HH, SS*HH, 768, NC);
  sigmoid_k<<<4,256,0,stream>>>(out_cl, out_cs, BB*NC, gsc, out_gs);
  // enriched = LN(hs + sigmoid(gs)*context)
  ln_k<<<BB*SS,256,0,stream>>>(hs, ctxt, gsc, lng, lnb, enrb, 0);
  // LAAT first (MFMA + tanh)
  split_k<<<(768*768+255)/256,256,0,stream>>>(lfw, Wdh, Wdl, 768*768);
  mfma(enrb, Wdh, Wdl, nullptr, Ub, nullptr, BB*SS, HH, HH, 1.f, 1);
  // att: M=4096, N=50 -> skinny (no bias)
  skinny(Ub, lsw, nullptr, attb, BB*SS, NL, HH, 768,768,NL);
  laat_softmax_k<<<(BB*NL+3)/4,256,0,stream>>>(attb, amask);
  label_reps_k<<<BB*NL,256,0,stream>>>(attb, enrb, out_lr);
  logits_k<<<(BB*NL+3)/4,256,0,stream>>>(out_lr, low, lob, out_cs, c2l, out_logits);
}